// Round 1
// baseline (366.649 us; speedup 1.0000x reference)
//
#include <hip/hip_runtime.h>
#include <math.h>

// NeuralMemory: chunked-parallel reformulation of the decaying rank-1 memory scan.
//   S_t = decay*S_{t-1} + s_t * v_t k_t^T ;  out_t = q_t^T S_{t-1}
// Chunk C=128, NC=16 chunks, b=4, s=2048, d_model=1024, d_mem=256.
//
// Pipeline:
//  1. proj GEMMs: k,v,q = x@W + b           (gemm64<false,false,0> x3)
//  2. gate:       s = sigmoid(x@Wg + bg)    (gate_kernel)
//  3. U_c = V^T diag(s_j decay^{127-j}) K   (gemm64<true,false,1>, per (b,c))
//  4. prefix scan over chunks: S_c states   (scan_kernel; writes final_state)
//  5. A_mask[i][j] = (q_i.v_j)*s_j*d^{i-1-j}, j<i  (gemm64<false,true,2>)
//  6. mem_out  = d^i * (Q @ S_c)            (gemm64<false,false,3>)
//  7. mem_out += A_mask @ K                 (gemm64<false,false,4>)
//  8. y = mem_out @ Wo + bo                 (gemm64<false,false,0>)

#define TILE 64
#define KT 32

struct GemmP {
  const float* A; long long a_bs; int lda;
  const float* B; long long b_bs; int ldb;
  float* C;       long long c_bs; int ldc;
  int M, N, K;
  int grid_n;
  const float* bias;
  const float* gate; long long gate_bs;
  const float* decay_ptr;
};

// AT: A stored [K][M] (stage direct). else A stored [M][K] (stage w/ transpose).
// BT: B stored [N][K] (stage w/ transpose). else B stored [K][N] (stage direct).
// EPI: 0=bias+store, 1=kscale(U)+store, 2=decay-mask store, 3=rowscale d^i store, 4=accumulate
template<bool AT, bool BT, int EPI>
__global__ __launch_bounds__(256)
void gemm64(GemmP p) {
  __shared__ float As[KT][TILE + 4];
  __shared__ float Bs[KT][TILE + 4];
  const int tid = threadIdx.x;
  const int bn = blockIdx.x % p.grid_n;
  const int bm = blockIdx.x / p.grid_n;
  const int m0 = bm * TILE, n0 = bn * TILE;
  const long long z = blockIdx.z;
  const float* A = p.A + z * p.a_bs;
  const float* B = p.B + z * p.b_bs;
  float* C = p.C + z * p.c_bs;

  float log2d = 0.f;
  if (EPI == 1 || EPI == 2 || EPI == 3) log2d = log2f(p.decay_ptr[0]);

  const int tx = tid & 15, ty = tid >> 4;
  float acc[4][4];
#pragma unroll
  for (int i = 0; i < 4; i++)
#pragma unroll
    for (int j = 0; j < 4; j++) acc[i][j] = 0.f;

  for (int k0 = 0; k0 < p.K; k0 += KT) {
    // ---- stage A tile into As[k][m] ----
    if (!AT) {
      int r = tid >> 2, kq = (tid & 3) * 8;
      const float* src = A + (long long)(m0 + r) * p.lda + k0 + kq;
      float4 a0 = *(const float4*)(src);
      float4 a1 = *(const float4*)(src + 4);
      As[kq + 0][r] = a0.x; As[kq + 1][r] = a0.y; As[kq + 2][r] = a0.z; As[kq + 3][r] = a0.w;
      As[kq + 4][r] = a1.x; As[kq + 5][r] = a1.y; As[kq + 6][r] = a1.z; As[kq + 7][r] = a1.w;
    } else {
      int kk = tid >> 3, mm = (tid & 7) * 8;
      const float* src = A + (long long)(k0 + kk) * p.lda + m0 + mm;
      float4 a0 = *(const float4*)(src);
      float4 a1 = *(const float4*)(src + 4);
      if (EPI == 1) {
        int kg = k0 + kk;
        float w = p.gate[z * p.gate_bs + kg] * exp2f((float)(127 - kg) * log2d);
        a0.x *= w; a0.y *= w; a0.z *= w; a0.w *= w;
        a1.x *= w; a1.y *= w; a1.z *= w; a1.w *= w;
      }
      *(float4*)&As[kk][mm] = a0;
      *(float4*)&As[kk][mm + 4] = a1;
    }
    // ---- stage B tile into Bs[k][n] ----
    if (!BT) {
      int kk = tid >> 3, nn = (tid & 7) * 8;
      const float* src = B + (long long)(k0 + kk) * p.ldb + n0 + nn;
      float4 b0 = *(const float4*)(src);
      float4 b1 = *(const float4*)(src + 4);
      *(float4*)&Bs[kk][nn] = b0;
      *(float4*)&Bs[kk][nn + 4] = b1;
    } else {
      int r = tid >> 2, kq = (tid & 3) * 8;
      const float* src = B + (long long)(n0 + r) * p.ldb + k0 + kq;
      float4 b0 = *(const float4*)(src);
      float4 b1 = *(const float4*)(src + 4);
      Bs[kq + 0][r] = b0.x; Bs[kq + 1][r] = b0.y; Bs[kq + 2][r] = b0.z; Bs[kq + 3][r] = b0.w;
      Bs[kq + 4][r] = b1.x; Bs[kq + 5][r] = b1.y; Bs[kq + 6][r] = b1.z; Bs[kq + 7][r] = b1.w;
    }
    __syncthreads();
#pragma unroll
    for (int kk = 0; kk < KT; kk++) {
      float4 av = *(const float4*)&As[kk][ty * 4];
      float4 bv = *(const float4*)&Bs[kk][tx * 4];
      float am[4] = {av.x, av.y, av.z, av.w};
      float bb[4] = {bv.x, bv.y, bv.z, bv.w};
#pragma unroll
      for (int i = 0; i < 4; i++)
#pragma unroll
        for (int j = 0; j < 4; j++)
          acc[i][j] = fmaf(am[i], bb[j], acc[i][j]);
    }
    __syncthreads();
  }

#pragma unroll
  for (int i = 0; i < 4; i++) {
    int gm = m0 + ty * 4 + i;
#pragma unroll
    for (int j = 0; j < 4; j++) {
      int gn = n0 + tx * 4 + j;
      float v = acc[i][j];
      long long cidx = (long long)gm * p.ldc + gn;
      if (EPI == 0) {
        if (p.bias) v += p.bias[gn];
        C[cidx] = v;
      } else if (EPI == 1) {
        C[cidx] = v;
      } else if (EPI == 2) {
        float out = 0.f;
        if (gn < gm)
          out = v * p.gate[z * p.gate_bs + gn] * exp2f((float)(gm - 1 - gn) * log2d);
        C[cidx] = out;
      } else if (EPI == 3) {
        C[cidx] = v * exp2f((float)gm * log2d);
      } else if (EPI == 4) {
        C[cidx] += v;
      }
    }
  }
}

__global__ __launch_bounds__(256)
void gate_kernel(const float* __restrict__ x, const float* __restrict__ Wg,
                 const float* __restrict__ bg, float* __restrict__ g, int nrows) {
  int wave = threadIdx.x >> 6;
  int lane = threadIdx.x & 63;
  int row = blockIdx.x * 4 + wave;
  if (row >= nrows) return;
  const float* xr = x + (long long)row * 1024;
  float s = 0.f;
  for (int d = lane; d < 1024; d += 64) s = fmaf(xr[d], Wg[d], s);
#pragma unroll
  for (int off = 32; off; off >>= 1) s += __shfl_xor(s, off, 64);
  if (lane == 0) g[row] = 1.f / (1.f + expf(-(s + bg[0])));
}

// In-place chunk-state prefix scan. U[b][c] on entry holds the chunk update U_c;
// on exit holds S_c (state BEFORE chunk c). Writes final state to out.
__global__ __launch_bounds__(256)
void scan_kernel(float* __restrict__ U, const float* __restrict__ state_in,
                 float* __restrict__ final_out, const float* __restrict__ decay_ptr) {
  int t = blockIdx.x * 256 + threadIdx.x;  // 0..262143
  int b = t >> 16, idx = t & 65535;
  float dC = exp2f(128.f * log2f(decay_ptr[0]));
  float cur = state_in[(long long)b * 65536 + idx];
#pragma unroll
  for (int c = 0; c < 16; c++) {
    long long off = ((long long)(b * 16 + c)) * 65536 + idx;
    float u = U[off];
    U[off] = cur;
    cur = fmaf(dC, cur, u);
  }
  final_out[(long long)b * 65536 + idx] = cur;
}

extern "C" void kernel_launch(void* const* d_in, const int* in_sizes, int n_in,
                              void* d_out, int out_size, void* d_ws, size_t ws_size,
                              hipStream_t stream) {
  const float* x     = (const float*)d_in[0];
  const float* state = (const float*)d_in[1];
  const float* Wk = (const float*)d_in[2];  const float* bk = (const float*)d_in[3];
  const float* Wv = (const float*)d_in[4];  const float* bv = (const float*)d_in[5];
  const float* Wq = (const float*)d_in[6];  const float* bq = (const float*)d_in[7];
  const float* Wo = (const float*)d_in[8];  const float* bo = (const float*)d_in[9];
  const float* Wg = (const float*)d_in[10]; const float* bg = (const float*)d_in[11];
  const float* decay = (const float*)d_in[12];

  float* out_y = (float*)d_out;              // [4][2048][1024]
  float* out_S = out_y + 8388608;            // [4][256][256]

  float* ws    = (float*)d_ws;
  float* kbuf  = ws;                // 2097152 floats  [4][2048][256]
  float* vbuf  = ws + 2097152;      // 2097152
  float* qbuf  = ws + 4194304;      // 2097152
  float* gbuf  = ws + 6291456;      // 8192     [4][2048]
  float* Ubuf  = ws + 6299648;      // 4194304  [64][256][256]  (U_c then S_c)
  float* Abuf  = ws + 10493952;     // 1048576  [64][128][128]
  float* mobuf = ws + 11542528;     // 2097152  [4][2048][256]

  // 1. projections k, v, q
  {
    GemmP p{};
    p.A = x; p.a_bs = 0; p.lda = 1024;
    p.b_bs = 0; p.ldb = 256;
    p.c_bs = 0; p.ldc = 256;
    p.M = 8192; p.N = 256; p.K = 1024; p.grid_n = 4;
    p.decay_ptr = decay;
    p.B = Wk; p.C = kbuf; p.bias = bk;
    gemm64<false, false, 0><<<dim3(512, 1, 1), 256, 0, stream>>>(p);
    p.B = Wv; p.C = vbuf; p.bias = bv;
    gemm64<false, false, 0><<<dim3(512, 1, 1), 256, 0, stream>>>(p);
    p.B = Wq; p.C = qbuf; p.bias = bq;
    gemm64<false, false, 0><<<dim3(512, 1, 1), 256, 0, stream>>>(p);
  }

  // 2. gate
  gate_kernel<<<2048, 256, 0, stream>>>(x, Wg, bg, gbuf, 8192);

  // 3. chunk updates U_c = V^T diag(w) K, per z = b*16+c
  {
    GemmP p{};
    p.A = vbuf; p.a_bs = 32768; p.lda = 256;   // [k=j][m=d]
    p.B = kbuf; p.b_bs = 32768; p.ldb = 256;   // [k=j][n=e]
    p.C = Ubuf; p.c_bs = 65536; p.ldc = 256;
    p.M = 256; p.N = 256; p.K = 128; p.grid_n = 4;
    p.gate = gbuf; p.gate_bs = 128; p.decay_ptr = decay;
    gemm64<true, false, 1><<<dim3(16, 1, 64), 256, 0, stream>>>(p);
  }

  // 4. chunk-state prefix scan (in place); writes final_state output
  scan_kernel<<<1024, 256, 0, stream>>>(Ubuf, state, out_S, decay);

  // 5. masked intra-chunk scores A[i][j] = (q_i . v_j) * s_j * d^{i-1-j}, j<i
  {
    GemmP p{};
    p.A = qbuf; p.a_bs = 32768; p.lda = 256;   // [m=i][k=d]
    p.B = vbuf; p.b_bs = 32768; p.ldb = 256;   // [n=j][k=d] -> BT
    p.C = Abuf; p.c_bs = 16384; p.ldc = 128;
    p.M = 128; p.N = 128; p.K = 256; p.grid_n = 2;
    p.gate = gbuf; p.gate_bs = 128; p.decay_ptr = decay;
    gemm64<false, true, 2><<<dim3(4, 1, 64), 256, 0, stream>>>(p);
  }

  // 6. inter: mem_out = d^i * (Q @ S_c)
  {
    GemmP p{};
    p.A = qbuf; p.a_bs = 32768; p.lda = 256;
    p.B = Ubuf; p.b_bs = 65536; p.ldb = 256;   // S_c after scan
    p.C = mobuf; p.c_bs = 32768; p.ldc = 256;
    p.M = 128; p.N = 256; p.K = 256; p.grid_n = 4;
    p.decay_ptr = decay;
    gemm64<false, false, 3><<<dim3(8, 1, 64), 256, 0, stream>>>(p);
  }

  // 7. intra: mem_out += A_mask @ K
  {
    GemmP p{};
    p.A = Abuf; p.a_bs = 16384; p.lda = 128;
    p.B = kbuf; p.b_bs = 32768; p.ldb = 256;
    p.C = mobuf; p.c_bs = 32768; p.ldc = 256;
    p.M = 128; p.N = 256; p.K = 128; p.grid_n = 4;
    p.decay_ptr = decay;
    gemm64<false, false, 4><<<dim3(8, 1, 64), 256, 0, stream>>>(p);
  }

  // 8. y = mem_out @ Wo + bo
  {
    GemmP p{};
    p.A = mobuf; p.a_bs = 0; p.lda = 256;
    p.B = Wo; p.b_bs = 0; p.ldb = 1024;
    p.C = out_y; p.c_bs = 0; p.ldc = 1024;
    p.M = 8192; p.N = 1024; p.K = 256; p.grid_n = 16;
    p.bias = bo; p.decay_ptr = decay;
    gemm64<false, false, 0><<<dim3(2048, 1, 1), 256, 0, stream>>>(p);
  }
}

// Round 2
// 145.525 us; speedup vs baseline: 2.5195x; 2.5195x over previous
//
#include <hip/hip_runtime.h>
#include <math.h>

// NeuralMemory: chunked-parallel reformulation of the decaying rank-1 memory scan.
//   S_t = decay*S_{t-1} + s_t * v_t k_t^T ;  out_t = q_t^T S_{t-1}
// Chunk C=128, NC=16 chunks, b=4, s=2048, d_model=1024, d_mem=256.
//
// Pipeline:
//  0. casts: x->bf16; Wk|Wv|Wq -> packed transposed bf16 [768][1024]; Wo -> [1024][256]
//  1. proj MFMA GEMM: kvq = x16 @ Wkvq^T + bias   (bf16 MFMA, fused k|v|q, N=768)
//  2. gate:  s = sigmoid(x@Wg + bg)
//  3. U_c = V^T diag(s_j decay^{127-j}) K          (fp32 gemm64, per (b,c))
//  4. prefix scan over chunks: S_c states          (writes final_state)
//  5. A_mask[i][j] = (q_i.v_j)*s_j*d^{i-1-j}, j<i  (fp32 gemm64)
//  6. mem_out  = d^i * (Q @ S_c)                   (fp32 gemm64)
//  7. mem_out += A_mask @ K -> write bf16 mo16     (fp32 gemm64, EPI5)
//  8. y = mo16 @ Wo^T + bo                         (bf16 MFMA)

#define TILE 64
#define KT 32

using bf16x8 = __attribute__((ext_vector_type(8))) short;
using f32x4  = __attribute__((ext_vector_type(4))) float;
using ushort8 = __attribute__((ext_vector_type(8))) unsigned short;

__device__ inline unsigned short f2bf(float f) {
  unsigned int u = __float_as_uint(f);
  u = (u + 0x7FFF + ((u >> 16) & 1)) >> 16;
  return (unsigned short)u;
}

// ---------------------------------------------------------------- fp32 GEMM
struct GemmP {
  const float* A; long long a_bs; int lda;
  const float* B; long long b_bs; int ldb;
  float* C;       long long c_bs; int ldc;
  int M, N, K;
  int grid_n;
  const float* bias;
  const float* gate; long long gate_bs;
  const float* decay_ptr;
  unsigned short* Cb; int ldcb;   // EPI5 bf16 output
};

// AT: A stored [K][M]. BT: B stored [N][K].
// EPI: 0=bias+store, 1=kscale(U)+store, 2=decay-mask store, 3=rowscale d^i store,
//      5=accumulate-with-C then store bf16 to Cb
template<bool AT, bool BT, int EPI>
__global__ __launch_bounds__(256)
void gemm64(GemmP p) {
  __shared__ float As[KT][TILE + 4];
  __shared__ float Bs[KT][TILE + 4];
  const int tid = threadIdx.x;
  const int bn = blockIdx.x % p.grid_n;
  const int bm = blockIdx.x / p.grid_n;
  const int m0 = bm * TILE, n0 = bn * TILE;
  const long long z = blockIdx.z;
  const float* A = p.A + z * p.a_bs;
  const float* B = p.B + z * p.b_bs;
  float* C = p.C + z * p.c_bs;

  float log2d = 0.f;
  if (EPI == 1 || EPI == 2 || EPI == 3) log2d = log2f(p.decay_ptr[0]);

  const int tx = tid & 15, ty = tid >> 4;
  float acc[4][4];
#pragma unroll
  for (int i = 0; i < 4; i++)
#pragma unroll
    for (int j = 0; j < 4; j++) acc[i][j] = 0.f;

  for (int k0 = 0; k0 < p.K; k0 += KT) {
    if (!AT) {
      int r = tid >> 2, kq = (tid & 3) * 8;
      const float* src = A + (long long)(m0 + r) * p.lda + k0 + kq;
      float4 a0 = *(const float4*)(src);
      float4 a1 = *(const float4*)(src + 4);
      As[kq + 0][r] = a0.x; As[kq + 1][r] = a0.y; As[kq + 2][r] = a0.z; As[kq + 3][r] = a0.w;
      As[kq + 4][r] = a1.x; As[kq + 5][r] = a1.y; As[kq + 6][r] = a1.z; As[kq + 7][r] = a1.w;
    } else {
      int kk = tid >> 3, mm = (tid & 7) * 8;
      const float* src = A + (long long)(k0 + kk) * p.lda + m0 + mm;
      float4 a0 = *(const float4*)(src);
      float4 a1 = *(const float4*)(src + 4);
      if (EPI == 1) {
        int kg = k0 + kk;
        float w = p.gate[z * p.gate_bs + kg] * exp2f((float)(127 - kg) * log2d);
        a0.x *= w; a0.y *= w; a0.z *= w; a0.w *= w;
        a1.x *= w; a1.y *= w; a1.z *= w; a1.w *= w;
      }
      *(float4*)&As[kk][mm] = a0;
      *(float4*)&As[kk][mm + 4] = a1;
    }
    if (!BT) {
      int kk = tid >> 3, nn = (tid & 7) * 8;
      const float* src = B + (long long)(k0 + kk) * p.ldb + n0 + nn;
      float4 b0 = *(const float4*)(src);
      float4 b1 = *(const float4*)(src + 4);
      *(float4*)&Bs[kk][nn] = b0;
      *(float4*)&Bs[kk][nn + 4] = b1;
    } else {
      int r = tid >> 2, kq = (tid & 3) * 8;
      const float* src = B + (long long)(n0 + r) * p.ldb + k0 + kq;
      float4 b0 = *(const float4*)(src);
      float4 b1 = *(const float4*)(src + 4);
      Bs[kq + 0][r] = b0.x; Bs[kq + 1][r] = b0.y; Bs[kq + 2][r] = b0.z; Bs[kq + 3][r] = b0.w;
      Bs[kq + 4][r] = b1.x; Bs[kq + 5][r] = b1.y; Bs[kq + 6][r] = b1.z; Bs[kq + 7][r] = b1.w;
    }
    __syncthreads();
#pragma unroll
    for (int kk = 0; kk < KT; kk++) {
      float4 av = *(const float4*)&As[kk][ty * 4];
      float4 bv = *(const float4*)&Bs[kk][tx * 4];
      float am[4] = {av.x, av.y, av.z, av.w};
      float bb[4] = {bv.x, bv.y, bv.z, bv.w};
#pragma unroll
      for (int i = 0; i < 4; i++)
#pragma unroll
        for (int j = 0; j < 4; j++)
          acc[i][j] = fmaf(am[i], bb[j], acc[i][j]);
    }
    __syncthreads();
  }

  unsigned short* Cb = p.Cb ? p.Cb + z * p.c_bs : nullptr;
#pragma unroll
  for (int i = 0; i < 4; i++) {
    int gm = m0 + ty * 4 + i;
#pragma unroll
    for (int j = 0; j < 4; j++) {
      int gn = n0 + tx * 4 + j;
      float v = acc[i][j];
      long long cidx = (long long)gm * p.ldc + gn;
      if (EPI == 0) {
        if (p.bias) v += p.bias[gn];
        C[cidx] = v;
      } else if (EPI == 1) {
        C[cidx] = v;
      } else if (EPI == 2) {
        float out = 0.f;
        if (gn < gm)
          out = v * p.gate[z * p.gate_bs + gn] * exp2f((float)(gm - 1 - gn) * log2d);
        C[cidx] = out;
      } else if (EPI == 3) {
        C[cidx] = v * exp2f((float)gm * log2d);
      } else if (EPI == 5) {
        float v2 = C[cidx] + v;
        Cb[(long long)gm * p.ldcb + gn] = f2bf(v2);
      }
    }
  }
}

// ---------------------------------------------------------------- bf16 MFMA GEMM
// C[M][N] = A[M][K](bf16) * Bt[N][K]^T(bf16) + bias. 128x128 tile, BK=64, 4 waves.
struct MfmaP {
  const unsigned short* A;  int lda;   // [M][K]
  const unsigned short* Bt; int ldb;   // [N][K]
  float* C; int ldc;
  int K, grid_n;
  const float* bias0; const float* bias1; const float* bias2;
};

// EPI: 0 = bias split in 3x256 chunks (packed kvq), 1 = single bias
template<int EPI>
__global__ __launch_bounds__(256)
void gemm_mfma(MfmaP p) {
  __shared__ unsigned short As[128 * 64];
  __shared__ unsigned short Bs[128 * 64];
  const int tid = threadIdx.x;
  const int bn = blockIdx.x % p.grid_n, bm = blockIdx.x / p.grid_n;
  const int m0 = bm * 128, n0 = bn * 128;
  const int lane = tid & 63, w = tid >> 6;
  const int wr = w >> 1, wc = w & 1;

  f32x4 acc[4][4] = {};

  const unsigned short* Abase = p.A + (long long)m0 * p.lda;
  const unsigned short* Bbase = p.Bt + (long long)n0 * p.ldb;
  const int srow = tid >> 3, scol = (tid & 7) * 8;

  for (int k0 = 0; k0 < p.K; k0 += 64) {
    if (k0) __syncthreads();
#pragma unroll
    for (int i = 0; i < 4; i++) {
      int row = i * 32 + srow;
      __builtin_amdgcn_global_load_lds(
          (const __attribute__((address_space(1))) unsigned int*)(Abase + (long long)row * p.lda + k0 + scol),
          (__attribute__((address_space(3))) unsigned int*)(&As[row * 64 + scol]), 16, 0, 0);
    }
#pragma unroll
    for (int i = 0; i < 4; i++) {
      int row = i * 32 + srow;
      __builtin_amdgcn_global_load_lds(
          (const __attribute__((address_space(1))) unsigned int*)(Bbase + (long long)row * p.ldb + k0 + scol),
          (__attribute__((address_space(3))) unsigned int*)(&Bs[row * 64 + scol]), 16, 0, 0);
    }
    __syncthreads();
#pragma unroll
    for (int kk = 0; kk < 2; kk++) {
      bf16x8 af[4], bfr[4];
      const int kb = kk * 32 + 8 * (lane >> 4);
#pragma unroll
      for (int m = 0; m < 4; m++)
        af[m] = *(const bf16x8*)&As[(wr * 64 + m * 16 + (lane & 15)) * 64 + kb];
#pragma unroll
      for (int n = 0; n < 4; n++)
        bfr[n] = *(const bf16x8*)&Bs[(wc * 64 + n * 16 + (lane & 15)) * 64 + kb];
#pragma unroll
      for (int m = 0; m < 4; m++)
#pragma unroll
        for (int n = 0; n < 4; n++)
          acc[m][n] = __builtin_amdgcn_mfma_f32_16x16x32_bf16(af[m], bfr[n], acc[m][n], 0, 0, 0);
    }
  }

  const int crow0 = m0 + wr * 64, ccol0 = n0 + wc * 64;
#pragma unroll
  for (int m = 0; m < 4; m++) {
#pragma unroll
    for (int n = 0; n < 4; n++) {
      int col = ccol0 + n * 16 + (lane & 15);
      float b;
      if (EPI == 0) {
        int s = col >> 8, c = col & 255;
        b = (s == 0 ? p.bias0[c] : s == 1 ? p.bias1[c] : p.bias2[c]);
      } else {
        b = p.bias0[col];
      }
#pragma unroll
      for (int q = 0; q < 4; q++) {
        int row = crow0 + m * 16 + (lane >> 4) * 4 + q;
        p.C[(long long)row * p.ldc + col] = acc[m][n][q] + b;
      }
    }
  }
}

// ---------------------------------------------------------------- casts
__global__ __launch_bounds__(256)
void cast_x_kernel(const float* __restrict__ x, unsigned short* __restrict__ out) {
  long long t = (long long)blockIdx.x * 256 + threadIdx.x;
  const float4* src = (const float4*)(x + t * 8);
  float4 a = src[0], b = src[1];
  ushort8 o;
  o[0] = f2bf(a.x); o[1] = f2bf(a.y); o[2] = f2bf(a.z); o[3] = f2bf(a.w);
  o[4] = f2bf(b.x); o[5] = f2bf(b.y); o[6] = f2bf(b.z); o[7] = f2bf(b.w);
  *(ushort8*)(out + t * 8) = o;
}

// dst[n][k] = src_sel[k][n] cast bf16. 64x64 tiles via LDS. srcCols per matrix.
__global__ __launch_bounds__(256)
void transpose_cast_kernel(const float* __restrict__ s0, const float* __restrict__ s1,
                           const float* __restrict__ s2, unsigned short* __restrict__ dst,
                           int srcRows, int srcCols, int ntiles_k) {
  __shared__ float tile[64][65];
  const int bk = blockIdx.x % ntiles_k, bnn = blockIdx.x / ntiles_k;
  const int k0 = bk * 64, n0g = bnn * 64;
  const int sel = n0g / srcCols;
  const int n0 = n0g - sel * srcCols;
  const float* S = sel == 0 ? s0 : sel == 1 ? s1 : s2;
  const int tid = threadIdx.x;
  const int rr = tid >> 4, c4 = (tid & 15) * 4;
#pragma unroll
  for (int pp = 0; pp < 4; pp++) {
    int r = pp * 16 + rr;
    float4 v = *(const float4*)&S[(long long)(k0 + r) * srcCols + n0 + c4];
    tile[r][c4 + 0] = v.x; tile[r][c4 + 1] = v.y; tile[r][c4 + 2] = v.z; tile[r][c4 + 3] = v.w;
  }
  __syncthreads();
  const int rn = tid >> 3, ck0 = (tid & 7) * 8;
#pragma unroll
  for (int pp = 0; pp < 2; pp++) {
    int n = pp * 32 + rn;
    ushort8 o;
#pragma unroll
    for (int j = 0; j < 8; j++) o[j] = f2bf(tile[ck0 + j][n]);
    *(ushort8*)&dst[(long long)(n0g + n) * srcRows + k0 + ck0] = o;
  }
}

// ---------------------------------------------------------------- gate & scan
__global__ __launch_bounds__(256)
void gate_kernel(const float* __restrict__ x, const float* __restrict__ Wg,
                 const float* __restrict__ bg, float* __restrict__ g, int nrows) {
  int wave = threadIdx.x >> 6;
  int lane = threadIdx.x & 63;
  int row = blockIdx.x * 4 + wave;
  if (row >= nrows) return;
  const float* xr = x + (long long)row * 1024;
  float s = 0.f;
  for (int d = lane; d < 1024; d += 64) s = fmaf(xr[d], Wg[d], s);
#pragma unroll
  for (int off = 32; off; off >>= 1) s += __shfl_xor(s, off, 64);
  if (lane == 0) g[row] = 1.f / (1.f + expf(-(s + bg[0])));
}

__global__ __launch_bounds__(256)
void scan_kernel(float* __restrict__ U, const float* __restrict__ state_in,
                 float* __restrict__ final_out, const float* __restrict__ decay_ptr) {
  int t = blockIdx.x * 256 + threadIdx.x;
  int b = t >> 16, idx = t & 65535;
  float dC = exp2f(128.f * log2f(decay_ptr[0]));
  float cur = state_in[(long long)b * 65536 + idx];
#pragma unroll
  for (int c = 0; c < 16; c++) {
    long long off = ((long long)(b * 16 + c)) * 65536 + idx;
    float u = U[off];
    U[off] = cur;
    cur = fmaf(dC, cur, u);
  }
  final_out[(long long)b * 65536 + idx] = cur;
}

// ---------------------------------------------------------------- launch
extern "C" void kernel_launch(void* const* d_in, const int* in_sizes, int n_in,
                              void* d_out, int out_size, void* d_ws, size_t ws_size,
                              hipStream_t stream) {
  const float* x     = (const float*)d_in[0];
  const float* state = (const float*)d_in[1];
  const float* Wk = (const float*)d_in[2];  const float* bk = (const float*)d_in[3];
  const float* Wv = (const float*)d_in[4];  const float* bv = (const float*)d_in[5];
  const float* Wq = (const float*)d_in[6];  const float* bq = (const float*)d_in[7];
  const float* Wo = (const float*)d_in[8];  const float* bo = (const float*)d_in[9];
  const float* Wg = (const float*)d_in[10]; const float* bg = (const float*)d_in[11];
  const float* decay = (const float*)d_in[12];

  float* out_y = (float*)d_out;              // [4][2048][1024]
  float* out_S = out_y + 8388608;            // [4][256][256]

  float* ws    = (float*)d_ws;
  float* kvq   = ws;                         // [8192][768] fp32 (k|v|q packed)
  float* gbuf  = ws + 6291456;               // [8192]
  float* Ubuf  = ws + 6299648;               // [64][256][256] (U_c then S_c)
  float* Abuf  = ws + 10493952;              // [64][128][128]
  float* mobuf = ws + 11542528;              // [4][2048][256] fp32
  unsigned short* wot16 = (unsigned short*)(ws + 13639680);  // [1024][256] bf16
  // aliases (lifetimes disjoint, stream-ordered):
  unsigned short* x16 = (unsigned short*)(ws + 6299648);     // [8192][1024] bf16, dead before Ubuf written
  unsigned short* w16 = (unsigned short*)(ws + 10493952);    // [768][1024] bf16, dead before Abuf written
  unsigned short* mo16 = (unsigned short*)(ws + 6299648);    // [8192][256] bf16, written after Ubuf last read

  // 0. casts
  cast_x_kernel<<<4096, 256, 0, stream>>>(x, x16);
  transpose_cast_kernel<<<192, 256, 0, stream>>>(Wk, Wv, Wq, w16, 1024, 256, 16);
  transpose_cast_kernel<<<64, 256, 0, stream>>>(Wo, Wo, Wo, wot16, 256, 1024, 4);

  // 1. fused projections kvq = x16 @ w16^T + bias
  {
    MfmaP p{};
    p.A = x16; p.lda = 1024;
    p.Bt = w16; p.ldb = 1024;
    p.C = kvq; p.ldc = 768;
    p.K = 1024; p.grid_n = 6;
    p.bias0 = bk; p.bias1 = bv; p.bias2 = bq;
    gemm_mfma<0><<<384, 256, 0, stream>>>(p);
  }

  // 2. gate
  gate_kernel<<<2048, 256, 0, stream>>>(x, Wg, bg, gbuf, 8192);

  // 3. chunk updates U_c = V^T diag(w) K
  {
    GemmP p{};
    p.A = kvq + 256; p.a_bs = 98304; p.lda = 768;
    p.B = kvq;       p.b_bs = 98304; p.ldb = 768;
    p.C = Ubuf;      p.c_bs = 65536; p.ldc = 256;
    p.M = 256; p.N = 256; p.K = 128; p.grid_n = 4;
    p.gate = gbuf; p.gate_bs = 128; p.decay_ptr = decay;
    gemm64<true, false, 1><<<dim3(16, 1, 64), 256, 0, stream>>>(p);
  }

  // 4. chunk-state prefix scan; writes final_state output
  scan_kernel<<<1024, 256, 0, stream>>>(Ubuf, state, out_S, decay);

  // 5. masked intra-chunk scores
  {
    GemmP p{};
    p.A = kvq + 512; p.a_bs = 98304; p.lda = 768;
    p.B = kvq + 256; p.b_bs = 98304; p.ldb = 768;
    p.C = Abuf;      p.c_bs = 16384; p.ldc = 128;
    p.M = 128; p.N = 128; p.K = 256; p.grid_n = 2;
    p.gate = gbuf; p.gate_bs = 128; p.decay_ptr = decay;
    gemm64<false, true, 2><<<dim3(4, 1, 64), 256, 0, stream>>>(p);
  }

  // 6. inter: mem_out = d^i * (Q @ S_c)
  {
    GemmP p{};
    p.A = kvq + 512; p.a_bs = 98304; p.lda = 768;
    p.B = Ubuf;      p.b_bs = 65536; p.ldb = 256;
    p.C = mobuf;     p.c_bs = 32768; p.ldc = 256;
    p.M = 128; p.N = 256; p.K = 256; p.grid_n = 4;
    p.decay_ptr = decay;
    gemm64<false, false, 3><<<dim3(8, 1, 64), 256, 0, stream>>>(p);
  }

  // 7. intra: mem_out += A_mask @ K ; emit bf16
  {
    GemmP p{};
    p.A = Abuf; p.a_bs = 16384; p.lda = 128;
    p.B = kvq;  p.b_bs = 98304; p.ldb = 768;
    p.C = mobuf; p.c_bs = 32768; p.ldc = 256;
    p.M = 128; p.N = 256; p.K = 128; p.grid_n = 4;
    p.decay_ptr = decay;
    p.Cb = mo16; p.ldcb = 256;
    gemm64<false, false, 5><<<dim3(8, 1, 64), 256, 0, stream>>>(p);
  }

  // 8. y = mo16 @ wot16^T + bo
  {
    MfmaP p{};
    p.A = mo16; p.lda = 256;
    p.Bt = wot16; p.ldb = 256;
    p.C = out_y; p.ldc = 1024;
    p.K = 256; p.grid_n = 8;
    p.bias0 = bo;
    gemm_mfma<1><<<512, 256, 0, stream>>>(p);
  }
}

// Round 3
// 120.137 us; speedup vs baseline: 3.0519x; 1.2113x over previous
//
#include <hip/hip_runtime.h>
#include <math.h>

// NeuralMemory: chunked-parallel decaying rank-1 memory scan, all-MFMA version.
//   S_t = decay*S_{t-1} + s_t * v_t k_t^T ;  out_t = q_t^T S_{t-1}
// Chunk C=128, NC=16, b=4, s=2048, d_model=1024, d_mem=256. All GEMMs bf16 MFMA.
//
//  1. cast_gate:   x -> x16 ; s = sigmoid(x@Wg+bg)
//  2. transpose_cast: Wk|Wv|Wq -> w16 [768][1024] ; Wo -> wot16 [1024][256]
//  3. proj MFMA:   k16,v16,qd16 = bf16(x16 @ w16^T + bias), qd scaled by d^i
//  4. trans_chunk: kT16[z][d][j] (plain), vTw16[z][d][j] (x s_j d^{127-j})
//  5. Ut MFMA:     Ut[z][e][d] = sum_j kT[e][j] vTw[d][j]       (= U_c^T, fp32)
//  6. scan:        T16[z] = bf16(S_c^T) running over chunks; writes final_state
//  7. scores MFMA: A16[z][i][j] = bf16( (qd_i.v_j) * s_j d^{-(j+1)} ), j<i
//  8. chunk_out MFMA (dual K-loop): mo16 = bf16( qd@T^T + A16@kT^T )
//  9. y MFMA:      out_y = mo16 @ wot16^T + bo

using bf16x8  = __attribute__((ext_vector_type(8))) short;
using f32x4   = __attribute__((ext_vector_type(4))) float;
using ushort8 = __attribute__((ext_vector_type(8))) unsigned short;

__device__ inline unsigned short f2bf(float f) {
  unsigned int u = __float_as_uint(f);
  u = (u + 0x7FFF + ((u >> 16) & 1)) >> 16;
  return (unsigned short)u;
}
__device__ inline float bf2f(unsigned short u) {
  return __uint_as_float(((unsigned int)u) << 16);
}

// ---------------------------------------------------------------- MFMA GEMM
// C = A[M][K] * B[N][K]^T, 128x128 tile, BK=64, 4 waves, global_load_lds staging.
struct MP {
  const unsigned short* A; long long a_bs; int lda;
  const unsigned short* B; long long b_bs; int ldb;
  const unsigned short* A2; long long a2_bs; int lda2;
  const unsigned short* B2; long long b2_bs; int ldb2;
  int K, K2, grid_n;
  float* Cf; unsigned short* Cb; long long c_bs; int ldc;
  const float* bias0; const float* bias1; const float* bias2;
  const float* gate;
  const float* decay_ptr;
  unsigned short* o_k; unsigned short* o_v; unsigned short* o_qd;
};

// EPI: 0=proj(bf16 k|v|qd split), 1=f32+bias (y), 2=f32 batched (Ut),
//      3=masked scores -> bf16, 4=bf16 batched (mem_out)
template<int EPI, bool DUAL>
__global__ __launch_bounds__(256)
void gemm_mfma(MP p) {
  __shared__ unsigned short As[128 * 64];
  __shared__ unsigned short Bs[128 * 64];
  const int tid = threadIdx.x;
  const int bn = blockIdx.x % p.grid_n, bm = blockIdx.x / p.grid_n;
  const int m0 = bm * 128, n0 = bn * 128;
  const long long z = blockIdx.z;
  const int lane = tid & 63, wv = tid >> 6;
  const int wr = wv >> 1, wc = wv & 1;
  const int srow = tid >> 3, scol = (tid & 7) * 8;

  f32x4 acc[4][4] = {};

  bool first = true;
#pragma unroll
  for (int pass = 0; pass < (DUAL ? 2 : 1); pass++) {
    const unsigned short* Abase;
    const unsigned short* Bbase;
    int lda, ldb, KK;
    if (DUAL && pass == 1) {
      Abase = p.A2 + z * p.a2_bs + (long long)m0 * p.lda2; lda = p.lda2;
      Bbase = p.B2 + z * p.b2_bs + (long long)n0 * p.ldb2; ldb = p.ldb2;
      KK = p.K2;
    } else {
      Abase = p.A + z * p.a_bs + (long long)m0 * p.lda; lda = p.lda;
      Bbase = p.B + z * p.b_bs + (long long)n0 * p.ldb; ldb = p.ldb;
      KK = p.K;
    }
    for (int k0 = 0; k0 < KK; k0 += 64) {
      if (!first) __syncthreads();
      first = false;
#pragma unroll
      for (int i = 0; i < 4; i++) {
        int row = i * 32 + srow;
        __builtin_amdgcn_global_load_lds(
            (const __attribute__((address_space(1))) unsigned int*)(Abase + (long long)row * lda + k0 + scol),
            (__attribute__((address_space(3))) unsigned int*)(&As[row * 64 + scol]), 16, 0, 0);
      }
#pragma unroll
      for (int i = 0; i < 4; i++) {
        int row = i * 32 + srow;
        __builtin_amdgcn_global_load_lds(
            (const __attribute__((address_space(1))) unsigned int*)(Bbase + (long long)row * ldb + k0 + scol),
            (__attribute__((address_space(3))) unsigned int*)(&Bs[row * 64 + scol]), 16, 0, 0);
      }
      __syncthreads();
#pragma unroll
      for (int kk = 0; kk < 2; kk++) {
        bf16x8 af[4], bfr[4];
        const int kb = kk * 32 + 8 * (lane >> 4);
#pragma unroll
        for (int m = 0; m < 4; m++)
          af[m] = *(const bf16x8*)&As[(wr * 64 + m * 16 + (lane & 15)) * 64 + kb];
#pragma unroll
        for (int n = 0; n < 4; n++)
          bfr[n] = *(const bf16x8*)&Bs[(wc * 64 + n * 16 + (lane & 15)) * 64 + kb];
#pragma unroll
        for (int m = 0; m < 4; m++)
#pragma unroll
          for (int n = 0; n < 4; n++)
            acc[m][n] = __builtin_amdgcn_mfma_f32_16x16x32_bf16(af[m], bfr[n], acc[m][n], 0, 0, 0);
      }
    }
  }

  const int crow0 = m0 + wr * 64, ccol0 = n0 + wc * 64;
  float log2d = 0.f;
  if (EPI == 0 || EPI == 3) log2d = log2f(p.decay_ptr[0]);
#pragma unroll
  for (int m = 0; m < 4; m++) {
#pragma unroll
    for (int n = 0; n < 4; n++) {
      int col = ccol0 + n * 16 + (lane & 15);
#pragma unroll
      for (int q = 0; q < 4; q++) {
        int row = crow0 + m * 16 + (lane >> 4) * 4 + q;
        float v = acc[m][n][q];
        if (EPI == 0) {
          int sel = col >> 8, c = col & 255;
          float bias = sel == 0 ? p.bias0[c] : sel == 1 ? p.bias1[c] : p.bias2[c];
          v += bias;
          if (sel == 0)      p.o_k[(long long)row * 256 + c] = f2bf(v);
          else if (sel == 1) p.o_v[(long long)row * 256 + c] = f2bf(v);
          else               p.o_qd[(long long)row * 256 + c] = f2bf(v * exp2f((float)(row & 127) * log2d));
        } else if (EPI == 1) {
          p.Cf[(long long)row * p.ldc + col] = v + p.bias0[col];
        } else if (EPI == 2) {
          p.Cf[z * p.c_bs + (long long)row * p.ldc + col] = v;
        } else if (EPI == 3) {
          float o = 0.f;
          if (col < row) o = v * p.gate[z * 128 + col] * exp2f(-(float)(col + 1) * log2d);
          p.Cb[z * p.c_bs + (long long)row * p.ldc + col] = f2bf(o);
        } else if (EPI == 4) {
          p.Cb[z * p.c_bs + (long long)row * p.ldc + col] = f2bf(v);
        }
      }
    }
  }
}

// ---------------------------------------------------------------- cast + gate
__global__ __launch_bounds__(256)
void cast_gate_kernel(const float* __restrict__ x, const float* __restrict__ Wg,
                      const float* __restrict__ bg, unsigned short* __restrict__ x16,
                      float* __restrict__ g) {
  const int wave = threadIdx.x >> 6, lane = threadIdx.x & 63;
  const long long row = (long long)blockIdx.x * 4 + wave;
  const float* xr = x + row * 1024 + lane * 16;
  const float* wr = Wg + lane * 16;
  float s = 0.f;
  ushort8 o0, o1;
#pragma unroll
  for (int qq = 0; qq < 2; qq++) {
    float4 a = *(const float4*)(xr + qq * 4);
    float4 w = *(const float4*)(wr + qq * 4);
    s = fmaf(a.x, w.x, s); s = fmaf(a.y, w.y, s);
    s = fmaf(a.z, w.z, s); s = fmaf(a.w, w.w, s);
    o0[qq * 4 + 0] = f2bf(a.x); o0[qq * 4 + 1] = f2bf(a.y);
    o0[qq * 4 + 2] = f2bf(a.z); o0[qq * 4 + 3] = f2bf(a.w);
  }
#pragma unroll
  for (int qq = 0; qq < 2; qq++) {
    float4 a = *(const float4*)(xr + 8 + qq * 4);
    float4 w = *(const float4*)(wr + 8 + qq * 4);
    s = fmaf(a.x, w.x, s); s = fmaf(a.y, w.y, s);
    s = fmaf(a.z, w.z, s); s = fmaf(a.w, w.w, s);
    o1[qq * 4 + 0] = f2bf(a.x); o1[qq * 4 + 1] = f2bf(a.y);
    o1[qq * 4 + 2] = f2bf(a.z); o1[qq * 4 + 3] = f2bf(a.w);
  }
  *(ushort8*)(x16 + row * 1024 + lane * 16) = o0;
  *(ushort8*)(x16 + row * 1024 + lane * 16 + 8) = o1;
#pragma unroll
  for (int off = 32; off; off >>= 1) s += __shfl_xor(s, off, 64);
  if (lane == 0) g[row] = 1.f / (1.f + expf(-(s + bg[0])));
}

// ---------------------------------------------------------------- weight transpose-casts
__global__ __launch_bounds__(256)
void transpose_cast_kernel(const float* __restrict__ s0, const float* __restrict__ s1,
                           const float* __restrict__ s2, unsigned short* __restrict__ dst,
                           int srcRows, int srcCols, int ntiles_k) {
  __shared__ float tile[64][65];
  const int bk = blockIdx.x % ntiles_k, bnn = blockIdx.x / ntiles_k;
  const int k0 = bk * 64, n0g = bnn * 64;
  const int sel = n0g / srcCols;
  const int n0 = n0g - sel * srcCols;
  const float* S = sel == 0 ? s0 : sel == 1 ? s1 : s2;
  const int tid = threadIdx.x;
  const int rr = tid >> 4, c4 = (tid & 15) * 4;
#pragma unroll
  for (int pp = 0; pp < 4; pp++) {
    int r = pp * 16 + rr;
    float4 v = *(const float4*)&S[(long long)(k0 + r) * srcCols + n0 + c4];
    tile[r][c4 + 0] = v.x; tile[r][c4 + 1] = v.y; tile[r][c4 + 2] = v.z; tile[r][c4 + 3] = v.w;
  }
  __syncthreads();
  const int rn = tid >> 3, ck0 = (tid & 7) * 8;
#pragma unroll
  for (int pp = 0; pp < 2; pp++) {
    int n = pp * 32 + rn;
    ushort8 o;
#pragma unroll
    for (int j = 0; j < 8; j++) o[j] = f2bf(tile[ck0 + j][n]);
    *(ushort8*)&dst[(long long)(n0g + n) * srcRows + k0 + ck0] = o;
  }
}

// ---------------------------------------------------------------- per-chunk k/v transpose
// src [8192 rows j][256 d] bf16 -> dst[z][256 d][128 j] bf16; vTw folds s_j*d^{127-j}.
__global__ __launch_bounds__(256)
void trans_chunk(const unsigned short* __restrict__ k16, const unsigned short* __restrict__ v16,
                 unsigned short* __restrict__ kT, unsigned short* __restrict__ vTw,
                 const float* __restrict__ gbuf, const float* __restrict__ decay_ptr) {
  __shared__ float tile[64][65];
  const int tid = threadIdx.x;
  const int jt = blockIdx.x & 1, dt = blockIdx.x >> 1;
  const int z = blockIdx.y, sel = blockIdx.z;
  const unsigned short* src = sel ? v16 : k16;
  const float log2d = log2f(decay_ptr[0]);
  const int rr = tid >> 4, c4 = (tid & 15) * 4;
#pragma unroll
  for (int pp = 0; pp < 4; pp++) {
    int r = pp * 16 + rr;               // j within tile
    int jl = jt * 64 + r;               // j within chunk
    float w = 1.f;
    if (sel) w = gbuf[z * 128 + jl] * exp2f((float)(127 - jl) * log2d);
    const unsigned short* s = src + ((long long)z * 128 + jl) * 256 + dt * 64 + c4;
    tile[r][c4 + 0] = w * bf2f(s[0]);
    tile[r][c4 + 1] = w * bf2f(s[1]);
    tile[r][c4 + 2] = w * bf2f(s[2]);
    tile[r][c4 + 3] = w * bf2f(s[3]);
  }
  __syncthreads();
  const int rn = tid >> 3, ck0 = (tid & 7) * 8;
  unsigned short* dstbuf = sel ? vTw : kT;
#pragma unroll
  for (int pp = 0; pp < 2; pp++) {
    int d = pp * 32 + rn;
    ushort8 o;
#pragma unroll
    for (int j = 0; j < 8; j++) o[j] = f2bf(tile[ck0 + j][d]);
    *(ushort8*)&dstbuf[(long long)z * 32768 + (long long)(dt * 64 + d) * 128 + jt * 64 + ck0] = o;
  }
}

// ---------------------------------------------------------------- chunk-state scan
// Ut[z][e][d] fp32 -> T16[z][e][d] = bf16(S_c^T) (state BEFORE chunk c);
// final_out[b][d][e] = final state.
__global__ __launch_bounds__(256)
void scan_kernel(const float* __restrict__ Ut, const float* __restrict__ state_in,
                 unsigned short* __restrict__ T16, float* __restrict__ final_out,
                 const float* __restrict__ decay_ptr) {
  int t = blockIdx.x * 256 + threadIdx.x;   // 0..262143
  int b = t >> 16, pidx = t & 65535;        // pidx = e*256+d
  int e = pidx >> 8, d = pidx & 255;
  float dC = exp2f(128.f * log2f(decay_ptr[0]));
  float cur = state_in[(long long)b * 65536 + d * 256 + e];
#pragma unroll
  for (int c = 0; c < 16; c++) {
    long long off = ((long long)(b * 16 + c)) * 65536 + pidx;
    T16[off] = f2bf(cur);
    cur = fmaf(dC, cur, Ut[off]);
  }
  final_out[(long long)b * 65536 + d * 256 + e] = cur;
}

// ---------------------------------------------------------------- launch
extern "C" void kernel_launch(void* const* d_in, const int* in_sizes, int n_in,
                              void* d_out, int out_size, void* d_ws, size_t ws_size,
                              hipStream_t stream) {
  const float* x     = (const float*)d_in[0];
  const float* state = (const float*)d_in[1];
  const float* Wk = (const float*)d_in[2];  const float* bk = (const float*)d_in[3];
  const float* Wv = (const float*)d_in[4];  const float* bv = (const float*)d_in[5];
  const float* Wq = (const float*)d_in[6];  const float* bq = (const float*)d_in[7];
  const float* Wo = (const float*)d_in[8];  const float* bo = (const float*)d_in[9];
  const float* Wg = (const float*)d_in[10]; const float* bg = (const float*)d_in[11];
  const float* decay = (const float*)d_in[12];

  float* out_y = (float*)d_out;              // [4][2048][1024]
  float* out_S = out_y + 8388608;            // [4][256][256]

  float* ws = (float*)d_ws;                  // ws_size ~268MB; usage ~71MB
  unsigned short* x16   = (unsigned short*)(ws);             // [8192][1024]
  unsigned short* k16   = (unsigned short*)(ws + 4194304);   // [8192][256]
  unsigned short* v16   = (unsigned short*)(ws + 5242880);   // [8192][256]
  unsigned short* qd16  = (unsigned short*)(ws + 6291456);   // [8192][256] (x d^i)
  unsigned short* w16   = (unsigned short*)(ws + 7340032);   // [768][1024]
  unsigned short* wot16 = (unsigned short*)(ws + 7733248);   // [1024][256]
  float*          gbuf  = ws + 7864320;                      // [8192]
  unsigned short* kT16  = (unsigned short*)(ws + 7872512);   // [64][256][128]
  unsigned short* vTw16 = (unsigned short*)(ws + 8921088);   // [64][256][128]
  float*          Ut    = ws + 9969664;                      // [64][256][256] fp32
  unsigned short* T16   = (unsigned short*)(ws + 14163968);  // [64][256][256]
  unsigned short* A16   = (unsigned short*)(ws + 16261120);  // [64][128][128]
  unsigned short* mo16  = (unsigned short*)(ws + 16785408);  // [8192][256]

  // 1. x -> bf16 + gate
  cast_gate_kernel<<<2048, 256, 0, stream>>>(x, Wg, bg, x16, gbuf);

  // 2. weight transposes
  transpose_cast_kernel<<<192, 256, 0, stream>>>(Wk, Wv, Wq, w16, 1024, 256, 16);
  transpose_cast_kernel<<<64, 256, 0, stream>>>(Wo, Wo, Wo, wot16, 256, 1024, 4);

  // 3. fused projections -> k16, v16, qd16 (bf16)
  {
    MP p{};
    p.A = x16; p.lda = 1024; p.B = w16; p.ldb = 1024;
    p.K = 1024; p.grid_n = 6;
    p.bias0 = bk; p.bias1 = bv; p.bias2 = bq;
    p.decay_ptr = decay;
    p.o_k = k16; p.o_v = v16; p.o_qd = qd16;
    gemm_mfma<0, false><<<dim3(384, 1, 1), 256, 0, stream>>>(p);
  }

  // 4. per-chunk transposes (kT plain, vTw gate-folded)
  trans_chunk<<<dim3(8, 64, 2), 256, 0, stream>>>(k16, v16, kT16, vTw16, gbuf, decay);

  // 5. Ut[z] = kT @ vTw^T  (256x256, K=128)
  {
    MP p{};
    p.A = kT16;  p.a_bs = 32768; p.lda = 128;
    p.B = vTw16; p.b_bs = 32768; p.ldb = 128;
    p.K = 128; p.grid_n = 2;
    p.Cf = Ut; p.c_bs = 65536; p.ldc = 256;
    p.decay_ptr = decay;
    gemm_mfma<2, false><<<dim3(4, 1, 64), 256, 0, stream>>>(p);
  }

  // 6. chunk-state scan -> T16 (bf16 S^T per chunk) + final_state
  scan_kernel<<<1024, 256, 0, stream>>>(Ut, state, T16, out_S, decay);

  // 7. masked intra scores -> A16[z] (128x128, K=256)
  {
    MP p{};
    p.A = qd16; p.a_bs = 32768; p.lda = 256;
    p.B = v16;  p.b_bs = 32768; p.ldb = 256;
    p.K = 256; p.grid_n = 1;
    p.Cb = A16; p.c_bs = 16384; p.ldc = 128;
    p.gate = gbuf; p.decay_ptr = decay;
    gemm_mfma<3, false><<<dim3(1, 1, 64), 256, 0, stream>>>(p);
  }

  // 8. mem_out = qd@T^T + A16@kT^T -> mo16 (128x256, K=256 then K=128)
  {
    MP p{};
    p.A = qd16; p.a_bs = 32768; p.lda = 256;
    p.B = T16;  p.b_bs = 65536; p.ldb = 256;
    p.K = 256;
    p.A2 = A16;  p.a2_bs = 16384; p.lda2 = 128;
    p.B2 = kT16; p.b2_bs = 32768; p.ldb2 = 128;
    p.K2 = 128;
    p.grid_n = 2;
    p.Cb = mo16; p.c_bs = 32768; p.ldc = 256;
    p.decay_ptr = decay;
    gemm_mfma<4, true><<<dim3(2, 1, 64), 256, 0, stream>>>(p);
  }

  // 9. y = mo16 @ wot16^T + bo
  {
    MP p{};
    p.A = mo16; p.lda = 256;
    p.B = wot16; p.ldb = 256;
    p.K = 256; p.grid_n = 8;
    p.Cf = out_y; p.ldc = 1024;
    p.bias0 = bo; p.decay_ptr = decay;
    gemm_mfma<1, false><<<dim3(512, 1, 1), 256, 0, stream>>>(p);
  }
}

// Round 4
// 101.616 us; speedup vs baseline: 3.6082x; 1.1823x over previous
//
#include <hip/hip_runtime.h>
#include <math.h>

// NeuralMemory: chunked-parallel decaying rank-1 memory scan, all-MFMA version.
//   S_t = decay*S_{t-1} + s_t * v_t k_t^T ;  out_t = q_t^T S_{t-1}
// Chunk C=128, NC=16, b=4, s=2048, d_model=1024, d_mem=256.
//
//  1. prep:        x -> x16 ; gate = sigmoid(x@Wg+bg) ; Wk|Wv|Wq -> w16 [768][1024];
//                  Wo -> wot16 [1024][256]            (single merged launch)
//  2. proj MFMA:   k16,v16,qd16 = bf16(x16 @ w16^T + bias), qd scaled by d^i
//  3. trans_chunk: kT16[z][d][j] (plain), vTw16[z][d][j] (x s_j d^{127-j})
//  4. Ut MFMA:     Ut16[z][e][d] = bf16(sum_j kT[e][j] vTw[d][j])   (= U_c^T)
//  5. scan:        T16[z] = bf16(S_c^T) running over chunks; writes final_state
//  6. chunk_attn:  A = mask(qd@v^T) in LDS (swizzled bf16);
//                  mo16 = bf16( qd@T^T + A@kT^T )      (fused, 8 waves, grid 2x64)
//  7. y MFMA:      out_y = mo16 @ wot16^T + bo

using bf16x8  = __attribute__((ext_vector_type(8))) short;
using f32x4   = __attribute__((ext_vector_type(4))) float;
using ushort8 = __attribute__((ext_vector_type(8))) unsigned short;

__device__ inline unsigned short f2bf(float f) {
  unsigned int u = __float_as_uint(f);
  u = (u + 0x7FFF + ((u >> 16) & 1)) >> 16;
  return (unsigned short)u;
}
__device__ inline float bf2f(unsigned short u) {
  return __uint_as_float(((unsigned int)u) << 16);
}

#define GLD_LDS(gsrc, ldst) \
  __builtin_amdgcn_global_load_lds( \
      (const __attribute__((address_space(1))) unsigned int*)(gsrc), \
      (__attribute__((address_space(3))) unsigned int*)(ldst), 16, 0, 0)

// ---------------------------------------------------------------- MFMA GEMM
// C = A[M][K] * B[N][K]^T, 128x128 tile, BK=64, 4 waves, global_load_lds staging.
struct MP {
  const unsigned short* A; long long a_bs; int lda;
  const unsigned short* B; long long b_bs; int ldb;
  int K, grid_n;
  float* Cf; unsigned short* Cb; long long c_bs; int ldc;
  const float* bias0; const float* bias1; const float* bias2;
  const float* decay_ptr;
  unsigned short* o_k; unsigned short* o_v; unsigned short* o_qd;
};

// EPI: 0=proj(bf16 k|v|qd split), 1=f32+bias (y), 4=bf16 batched (Ut)
template<int EPI>
__global__ __launch_bounds__(256)
void gemm_mfma(MP p) {
  __shared__ unsigned short As[128 * 64];
  __shared__ unsigned short Bs[128 * 64];
  const int tid = threadIdx.x;
  const int bn = blockIdx.x % p.grid_n, bm = blockIdx.x / p.grid_n;
  const int m0 = bm * 128, n0 = bn * 128;
  const long long z = blockIdx.z;
  const int lane = tid & 63, wv = tid >> 6;
  const int wr = wv >> 1, wc = wv & 1;
  const int srow = tid >> 3, scol = (tid & 7) * 8;

  f32x4 acc[4][4] = {};

  const unsigned short* Abase = p.A + z * p.a_bs + (long long)m0 * p.lda;
  const unsigned short* Bbase = p.B + z * p.b_bs + (long long)n0 * p.ldb;

  for (int k0 = 0; k0 < p.K; k0 += 64) {
    if (k0) __syncthreads();
#pragma unroll
    for (int i = 0; i < 4; i++) {
      int row = i * 32 + srow;
      GLD_LDS(Abase + (long long)row * p.lda + k0 + scol, &As[row * 64 + scol]);
    }
#pragma unroll
    for (int i = 0; i < 4; i++) {
      int row = i * 32 + srow;
      GLD_LDS(Bbase + (long long)row * p.ldb + k0 + scol, &Bs[row * 64 + scol]);
    }
    __syncthreads();
#pragma unroll
    for (int kk = 0; kk < 2; kk++) {
      bf16x8 af[4], bfr[4];
      const int kb = kk * 32 + 8 * (lane >> 4);
#pragma unroll
      for (int m = 0; m < 4; m++)
        af[m] = *(const bf16x8*)&As[(wr * 64 + m * 16 + (lane & 15)) * 64 + kb];
#pragma unroll
      for (int n = 0; n < 4; n++)
        bfr[n] = *(const bf16x8*)&Bs[(wc * 64 + n * 16 + (lane & 15)) * 64 + kb];
#pragma unroll
      for (int m = 0; m < 4; m++)
#pragma unroll
        for (int n = 0; n < 4; n++)
          acc[m][n] = __builtin_amdgcn_mfma_f32_16x16x32_bf16(af[m], bfr[n], acc[m][n], 0, 0, 0);
    }
  }

  const int crow0 = m0 + wr * 64, ccol0 = n0 + wc * 64;
  float log2d = 0.f;
  if (EPI == 0) log2d = log2f(p.decay_ptr[0]);
#pragma unroll
  for (int m = 0; m < 4; m++) {
#pragma unroll
    for (int n = 0; n < 4; n++) {
      int col = ccol0 + n * 16 + (lane & 15);
#pragma unroll
      for (int q = 0; q < 4; q++) {
        int row = crow0 + m * 16 + (lane >> 4) * 4 + q;
        float v = acc[m][n][q];
        if (EPI == 0) {
          int sel = col >> 8, c = col & 255;
          float bias = sel == 0 ? p.bias0[c] : sel == 1 ? p.bias1[c] : p.bias2[c];
          v += bias;
          if (sel == 0)      p.o_k[(long long)row * 256 + c] = f2bf(v);
          else if (sel == 1) p.o_v[(long long)row * 256 + c] = f2bf(v);
          else               p.o_qd[(long long)row * 256 + c] = f2bf(v * exp2f((float)(row & 127) * log2d));
        } else if (EPI == 1) {
          p.Cf[(long long)row * p.ldc + col] = v + p.bias0[col];
        } else if (EPI == 4) {
          p.Cb[z * p.c_bs + (long long)row * p.ldc + col] = f2bf(v);
        }
      }
    }
  }
}

// ---------------------------------------------------------------- fused chunk attention
// Per (nh, z): phase 1  A[i][j] = (qd_i . v_j) * s_j * d^{-(j+1)} (j<i) -> LDS bf16 (swizzled)
//              phase 2  mo[i][d] = qd@T^T + A@kT^T  for d in [nh*128, nh*128+128)
__global__ __launch_bounds__(512)
void chunk_attn(const unsigned short* __restrict__ qd16, const unsigned short* __restrict__ v16,
                const unsigned short* __restrict__ kT16, const unsigned short* __restrict__ T16,
                unsigned short* __restrict__ mo16, const float* __restrict__ gbuf,
                const float* __restrict__ decay_ptr) {
  __shared__ unsigned short As[128 * 64];
  __shared__ unsigned short Bs[128 * 64];
  __shared__ unsigned short Al[128 * 128];   // swizzled score tile
  const int tid = threadIdx.x;
  const int nh = blockIdx.x;                 // 0/1: which 128-col half of mo
  const int z = blockIdx.z;
  const int lane = tid & 63, wv = tid >> 6;  // 8 waves
  const int wr = wv >> 2, wc = wv & 3;       // 2 x 4
  const int srow = tid >> 3, scol = (tid & 7) * 8;
  const float log2d = log2f(decay_ptr[0]);

  const unsigned short* qz = qd16 + (long long)z * 32768;
  const unsigned short* vz = v16 + (long long)z * 32768;

  // ---- phase 1: A = masked(qd @ v^T), K=256 ----
  f32x4 acc1[4][2] = {};
  for (int k0 = 0; k0 < 256; k0 += 64) {
    if (k0) __syncthreads();
#pragma unroll
    for (int i = 0; i < 2; i++) {
      int row = i * 64 + srow;
      GLD_LDS(qz + (long long)row * 256 + k0 + scol, &As[row * 64 + scol]);
      GLD_LDS(vz + (long long)row * 256 + k0 + scol, &Bs[row * 64 + scol]);
    }
    __syncthreads();
#pragma unroll
    for (int kk = 0; kk < 2; kk++) {
      bf16x8 af[4], bfr[2];
      const int kb = kk * 32 + 8 * (lane >> 4);
#pragma unroll
      for (int m = 0; m < 4; m++)
        af[m] = *(const bf16x8*)&As[(wr * 64 + m * 16 + (lane & 15)) * 64 + kb];
#pragma unroll
      for (int n = 0; n < 2; n++)
        bfr[n] = *(const bf16x8*)&Bs[(wc * 32 + n * 16 + (lane & 15)) * 64 + kb];
#pragma unroll
      for (int m = 0; m < 4; m++)
#pragma unroll
        for (int n = 0; n < 2; n++)
          acc1[m][n] = __builtin_amdgcn_mfma_f32_16x16x32_bf16(af[m], bfr[n], acc1[m][n], 0, 0, 0);
    }
  }
  // epilogue -> Al (mask, gate-scale, bf16, XOR-swizzled)
#pragma unroll
  for (int n = 0; n < 2; n++) {
    int col = wc * 32 + n * 16 + (lane & 15);
    float gsc = gbuf[z * 128 + col] * exp2f(-(float)(col + 1) * log2d);
#pragma unroll
    for (int m = 0; m < 4; m++) {
#pragma unroll
      for (int q = 0; q < 4; q++) {
        int row = wr * 64 + m * 16 + (lane >> 4) * 4 + q;
        float v = (col < row) ? acc1[m][n][q] * gsc : 0.f;
        int byteoff = (row * 256 + col * 2) ^ ((row & 7) << 4);
        *(unsigned short*)((char*)Al + byteoff) = f2bf(v);
      }
    }
  }
  __syncthreads();  // Al visible; As/Bs free for reuse

  // ---- phase 2: mo = qd@T^T + A@kT^T (this block: cols nh*128..nh*128+127) ----
  f32x4 acc2[4][2] = {};
  const unsigned short* Tz = T16 + (long long)z * 65536 + (long long)nh * 128 * 256;
  for (int k0 = 0; k0 < 256; k0 += 64) {
    if (k0) __syncthreads();
#pragma unroll
    for (int i = 0; i < 2; i++) {
      int row = i * 64 + srow;
      GLD_LDS(qz + (long long)row * 256 + k0 + scol, &As[row * 64 + scol]);
      GLD_LDS(Tz + (long long)row * 256 + k0 + scol, &Bs[row * 64 + scol]);
    }
    __syncthreads();
#pragma unroll
    for (int kk = 0; kk < 2; kk++) {
      bf16x8 af[4], bfr[2];
      const int kb = kk * 32 + 8 * (lane >> 4);
#pragma unroll
      for (int m = 0; m < 4; m++)
        af[m] = *(const bf16x8*)&As[(wr * 64 + m * 16 + (lane & 15)) * 64 + kb];
#pragma unroll
      for (int n = 0; n < 2; n++)
        bfr[n] = *(const bf16x8*)&Bs[(wc * 32 + n * 16 + (lane & 15)) * 64 + kb];
#pragma unroll
      for (int m = 0; m < 4; m++)
#pragma unroll
        for (int n = 0; n < 2; n++)
          acc2[m][n] = __builtin_amdgcn_mfma_f32_16x16x32_bf16(af[m], bfr[n], acc2[m][n], 0, 0, 0);
    }
  }
  const unsigned short* kTz = kT16 + (long long)z * 32768 + (long long)nh * 128 * 128;
  for (int k0 = 0; k0 < 128; k0 += 64) {
    __syncthreads();
#pragma unroll
    for (int i = 0; i < 2; i++) {
      int row = i * 64 + srow;
      GLD_LDS(kTz + (long long)row * 128 + k0 + scol, &Bs[row * 64 + scol]);
    }
    __syncthreads();
#pragma unroll
    for (int kk = 0; kk < 2; kk++) {
      bf16x8 af[4], bfr[2];
      const int kb = k0 + kk * 32 + 8 * (lane >> 4);
#pragma unroll
      for (int m = 0; m < 4; m++) {
        int row = wr * 64 + m * 16 + (lane & 15);
        int byteoff = (row * 256 + kb * 2) ^ ((row & 7) << 4);
        af[m] = *(const bf16x8*)((char*)Al + byteoff);
      }
#pragma unroll
      for (int n = 0; n < 2; n++)
        bfr[n] = *(const bf16x8*)&Bs[(wc * 32 + n * 16 + (lane & 15)) * 64 + kk * 32 + 8 * (lane >> 4)];
#pragma unroll
      for (int m = 0; m < 4; m++)
#pragma unroll
        for (int n = 0; n < 2; n++)
          acc2[m][n] = __builtin_amdgcn_mfma_f32_16x16x32_bf16(af[m], bfr[n], acc2[m][n], 0, 0, 0);
    }
  }
  // epilogue -> mo16
#pragma unroll
  for (int m = 0; m < 4; m++) {
#pragma unroll
    for (int n = 0; n < 2; n++) {
      int col = wc * 32 + n * 16 + (lane & 15);
#pragma unroll
      for (int q = 0; q < 4; q++) {
        int row = wr * 64 + m * 16 + (lane >> 4) * 4 + q;
        mo16[((long long)z * 128 + row) * 256 + nh * 128 + col] = f2bf(acc2[m][n][q]);
      }
    }
  }
}

// ---------------------------------------------------------------- prep (cast+gate+weight transposes)
__global__ __launch_bounds__(256)
void prep_kernel(const float* __restrict__ x, const float* __restrict__ Wg,
                 const float* __restrict__ bg, unsigned short* __restrict__ x16,
                 float* __restrict__ g,
                 const float* __restrict__ Wk, const float* __restrict__ Wv,
                 const float* __restrict__ Wq, unsigned short* __restrict__ w16,
                 const float* __restrict__ Wo, unsigned short* __restrict__ wot16) {
  __shared__ float tile[64][65];
  const int bx = blockIdx.x;
  const int tid = threadIdx.x;
  if (bx < 2048) {
    // cast x -> bf16 rows + gate
    const int wave = tid >> 6, lane = tid & 63;
    const long long row = (long long)bx * 4 + wave;
    const float* xr = x + row * 1024 + lane * 16;
    const float* wr = Wg + lane * 16;
    float s = 0.f;
    ushort8 o0, o1;
#pragma unroll
    for (int qq = 0; qq < 2; qq++) {
      float4 a = *(const float4*)(xr + qq * 4);
      float4 w = *(const float4*)(wr + qq * 4);
      s = fmaf(a.x, w.x, s); s = fmaf(a.y, w.y, s);
      s = fmaf(a.z, w.z, s); s = fmaf(a.w, w.w, s);
      o0[qq * 4 + 0] = f2bf(a.x); o0[qq * 4 + 1] = f2bf(a.y);
      o0[qq * 4 + 2] = f2bf(a.z); o0[qq * 4 + 3] = f2bf(a.w);
    }
#pragma unroll
    for (int qq = 0; qq < 2; qq++) {
      float4 a = *(const float4*)(xr + 8 + qq * 4);
      float4 w = *(const float4*)(wr + 8 + qq * 4);
      s = fmaf(a.x, w.x, s); s = fmaf(a.y, w.y, s);
      s = fmaf(a.z, w.z, s); s = fmaf(a.w, w.w, s);
      o1[qq * 4 + 0] = f2bf(a.x); o1[qq * 4 + 1] = f2bf(a.y);
      o1[qq * 4 + 2] = f2bf(a.z); o1[qq * 4 + 3] = f2bf(a.w);
    }
    *(ushort8*)(x16 + row * 1024 + lane * 16) = o0;
    *(ushort8*)(x16 + row * 1024 + lane * 16 + 8) = o1;
#pragma unroll
    for (int off = 32; off; off >>= 1) s += __shfl_xor(s, off, 64);
    if (lane == 0) g[row] = 1.f / (1.f + expf(-(s + bg[0])));
    return;
  }
  // weight transpose-cast
  int t = bx - 2048;
  const float* S; unsigned short* dst;
  int srcCols, dstLd, k0, n0g, n0;
  if (t < 192) {                 // Wk|Wv|Wq -> w16 [768][1024]
    k0 = (t % 16) * 64; n0g = (t / 16) * 64;
    int sel = n0g >> 8; n0 = n0g - (sel << 8);
    S = sel == 0 ? Wk : sel == 1 ? Wv : Wq;
    srcCols = 256; dst = w16; dstLd = 1024;
  } else {                       // Wo -> wot16 [1024][256]
    t -= 192;
    k0 = (t % 4) * 64; n0g = (t / 4) * 64; n0 = n0g;
    S = Wo; srcCols = 1024; dst = wot16; dstLd = 256;
  }
  const int rr = tid >> 4, c4 = (tid & 15) * 4;
#pragma unroll
  for (int pp = 0; pp < 4; pp++) {
    int r = pp * 16 + rr;
    float4 v = *(const float4*)&S[(long long)(k0 + r) * srcCols + n0 + c4];
    tile[r][c4 + 0] = v.x; tile[r][c4 + 1] = v.y; tile[r][c4 + 2] = v.z; tile[r][c4 + 3] = v.w;
  }
  __syncthreads();
  const int rn = tid >> 3, ck0 = (tid & 7) * 8;
#pragma unroll
  for (int pp = 0; pp < 2; pp++) {
    int n = pp * 32 + rn;
    ushort8 o;
#pragma unroll
    for (int j = 0; j < 8; j++) o[j] = f2bf(tile[ck0 + j][n]);
    *(ushort8*)&dst[(long long)(n0g + n) * dstLd + k0 + ck0] = o;
  }
}

// ---------------------------------------------------------------- per-chunk k/v transpose
__global__ __launch_bounds__(256)
void trans_chunk(const unsigned short* __restrict__ k16, const unsigned short* __restrict__ v16,
                 unsigned short* __restrict__ kT, unsigned short* __restrict__ vTw,
                 const float* __restrict__ gbuf, const float* __restrict__ decay_ptr) {
  __shared__ float tile[64][65];
  const int tid = threadIdx.x;
  const int jt = blockIdx.x & 1, dt = blockIdx.x >> 1;
  const int z = blockIdx.y, sel = blockIdx.z;
  const unsigned short* src = sel ? v16 : k16;
  const float log2d = log2f(decay_ptr[0]);
  const int rr = tid >> 4, c4 = (tid & 15) * 4;
#pragma unroll
  for (int pp = 0; pp < 4; pp++) {
    int r = pp * 16 + rr;
    int jl = jt * 64 + r;
    float w = 1.f;
    if (sel) w = gbuf[z * 128 + jl] * exp2f((float)(127 - jl) * log2d);
    const unsigned short* s = src + ((long long)z * 128 + jl) * 256 + dt * 64 + c4;
    tile[r][c4 + 0] = w * bf2f(s[0]);
    tile[r][c4 + 1] = w * bf2f(s[1]);
    tile[r][c4 + 2] = w * bf2f(s[2]);
    tile[r][c4 + 3] = w * bf2f(s[3]);
  }
  __syncthreads();
  const int rn = tid >> 3, ck0 = (tid & 7) * 8;
  unsigned short* dstbuf = sel ? vTw : kT;
#pragma unroll
  for (int pp = 0; pp < 2; pp++) {
    int d = pp * 32 + rn;
    ushort8 o;
#pragma unroll
    for (int j = 0; j < 8; j++) o[j] = f2bf(tile[ck0 + j][d]);
    *(ushort8*)&dstbuf[(long long)z * 32768 + (long long)(dt * 64 + d) * 128 + jt * 64 + ck0] = o;
  }
}

// ---------------------------------------------------------------- chunk-state scan
__global__ __launch_bounds__(256)
void scan_kernel(const unsigned short* __restrict__ Ut16, const float* __restrict__ state_in,
                 unsigned short* __restrict__ T16, float* __restrict__ final_out,
                 const float* __restrict__ decay_ptr) {
  int t = blockIdx.x * 256 + threadIdx.x;   // 0..262143
  int b = t >> 16, pidx = t & 65535;        // pidx = e*256+d
  int e = pidx >> 8, d = pidx & 255;
  float dC = exp2f(128.f * log2f(decay_ptr[0]));
  float cur = state_in[(long long)b * 65536 + d * 256 + e];
#pragma unroll
  for (int c = 0; c < 16; c++) {
    long long off = ((long long)(b * 16 + c)) * 65536 + pidx;
    T16[off] = f2bf(cur);
    cur = fmaf(dC, cur, bf2f(Ut16[off]));
  }
  final_out[(long long)b * 65536 + d * 256 + e] = cur;
}

// ---------------------------------------------------------------- launch
extern "C" void kernel_launch(void* const* d_in, const int* in_sizes, int n_in,
                              void* d_out, int out_size, void* d_ws, size_t ws_size,
                              hipStream_t stream) {
  const float* x     = (const float*)d_in[0];
  const float* state = (const float*)d_in[1];
  const float* Wk = (const float*)d_in[2];  const float* bk = (const float*)d_in[3];
  const float* Wv = (const float*)d_in[4];  const float* bv = (const float*)d_in[5];
  const float* Wq = (const float*)d_in[6];  const float* bq = (const float*)d_in[7];
  const float* Wo = (const float*)d_in[8];  const float* bo = (const float*)d_in[9];
  const float* Wg = (const float*)d_in[10]; const float* bg = (const float*)d_in[11];
  const float* decay = (const float*)d_in[12];

  float* out_y = (float*)d_out;              // [4][2048][1024]
  float* out_S = out_y + 8388608;            // [4][256][256]

  float* ws = (float*)d_ws;
  unsigned short* x16   = (unsigned short*)(ws);             // [8192][1024]
  unsigned short* k16   = (unsigned short*)(ws + 4194304);   // [8192][256]
  unsigned short* v16   = (unsigned short*)(ws + 5242880);
  unsigned short* qd16  = (unsigned short*)(ws + 6291456);   // q * d^i
  unsigned short* w16   = (unsigned short*)(ws + 7340032);   // [768][1024]
  unsigned short* wot16 = (unsigned short*)(ws + 7733248);   // [1024][256]
  float*          gbuf  = ws + 7864320;                      // [8192]
  unsigned short* kT16  = (unsigned short*)(ws + 7872512);   // [64][256][128]
  unsigned short* vTw16 = (unsigned short*)(ws + 8921088);   // [64][256][128]
  unsigned short* Ut16  = (unsigned short*)(ws + 9969664);   // [64][256][256]
  unsigned short* T16   = (unsigned short*)(ws + 12066816);  // [64][256][256]
  unsigned short* mo16  = (unsigned short*)(ws + 14163968);  // [8192][256]

  // 1. prep: cast+gate + weight transposes
  prep_kernel<<<2304, 256, 0, stream>>>(x, Wg, bg, x16, gbuf, Wk, Wv, Wq, w16, Wo, wot16);

  // 2. fused projections -> k16, v16, qd16
  {
    MP p{};
    p.A = x16; p.lda = 1024; p.B = w16; p.ldb = 1024;
    p.K = 1024; p.grid_n = 6;
    p.bias0 = bk; p.bias1 = bv; p.bias2 = bq;
    p.decay_ptr = decay;
    p.o_k = k16; p.o_v = v16; p.o_qd = qd16;
    gemm_mfma<0><<<dim3(384, 1, 1), 256, 0, stream>>>(p);
  }

  // 3. per-chunk transposes
  trans_chunk<<<dim3(8, 64, 2), 256, 0, stream>>>(k16, v16, kT16, vTw16, gbuf, decay);

  // 4. Ut[z] = kT @ vTw^T -> bf16
  {
    MP p{};
    p.A = kT16;  p.a_bs = 32768; p.lda = 128;
    p.B = vTw16; p.b_bs = 32768; p.ldb = 128;
    p.K = 128; p.grid_n = 2;
    p.Cb = Ut16; p.c_bs = 65536; p.ldc = 256;
    p.decay_ptr = decay;
    gemm_mfma<4><<<dim3(4, 1, 64), 256, 0, stream>>>(p);
  }

  // 5. chunk-state scan -> T16 + final_state
  scan_kernel<<<1024, 256, 0, stream>>>(Ut16, state, T16, out_S, decay);

  // 6. fused scores + mem_out
  chunk_attn<<<dim3(2, 1, 64), 512, 0, stream>>>(qd16, v16, kT16, T16, mo16, gbuf, decay);

  // 7. y = mo16 @ wot16^T + bo
  {
    MP p{};
    p.A = mo16; p.lda = 256;
    p.B = wot16; p.ldb = 256;
    p.K = 256; p.grid_n = 8;
    p.Cf = out_y; p.ldc = 1024;
    p.bias0 = bo; p.decay_ptr = decay;
    gemm_mfma<1><<<dim3(512, 1, 1), 256, 0, stream>>>(p);
  }
}

// Round 6
// 94.682 us; speedup vs baseline: 3.8724x; 1.0732x over previous
//
#include <hip/hip_runtime.h>
#include <math.h>

// NeuralMemory: chunked-parallel decaying rank-1 memory scan, all-MFMA version.
//   S_t = decay*S_{t-1} + s_t * v_t k_t^T ;  out_t = q_t^T S_{t-1}
// Chunk C=128, NC=16, b=4, s=2048, d_model=1024, d_mem=256.
//
//  1. prep:      x -> x16 ; gate = sigmoid(x@Wg+bg) ; Wk|Wv|Wq -> w16 ; Wo -> wot16
//  2. proj MFMA: v16, qd16 (qd = q * d^i) = bf16(x16 @ w16^T + bias); epilogue
//                LDS-transposes k/v tiles -> kT16[z][d][j], vTw16[z][d][j] (gate-folded)
//  3. Ut MFMA:   Ut16[z][e][d] = bf16(sum_j kT[e][j] vTw[d][j])   (= U_c^T)
//  4. scan:      T16[z] = bf16(S_c^T) running over chunks; writes final_state
//  5. chunk_attn (per nh,rh,z): A(64x128 rows rh) = mask(qd@v^T) -> LDS swizzled;
//                mo16[64 rows][128 cols nh] = qd@T^T + A@kT^T    (p1/p2a fused)
//  6. y MFMA:    out_y = mo16 @ wot16^T + bo

using bf16x8 = __attribute__((ext_vector_type(8))) short;
using f32x4  = __attribute__((ext_vector_type(4))) float;
using u16x4  = __attribute__((ext_vector_type(4))) unsigned short;
using u16x8  = __attribute__((ext_vector_type(8))) unsigned short;

__device__ inline unsigned short f2bf(float f) {
  unsigned int u = __float_as_uint(f);
  u = (u + 0x7FFF + ((u >> 16) & 1)) >> 16;
  return (unsigned short)u;
}
__device__ inline float bf2f(unsigned short u) {
  return __uint_as_float(((unsigned int)u) << 16);
}

#define GLD_LDS(gsrc, ldst) \
  __builtin_amdgcn_global_load_lds( \
      (const __attribute__((address_space(1))) unsigned int*)(gsrc), \
      (__attribute__((address_space(3))) unsigned int*)(ldst), 16, 0, 0)

// ---------------------------------------------------------------- MFMA GEMM
// C = A[M][K] * B[N][K]^T, 128x128 tile, BK=64, 4 waves, global_load_lds staging.
struct MP {
  const unsigned short* A; long long a_bs; int lda;
  const unsigned short* B; long long b_bs; int ldb;
  int K, grid_n;
  float* Cf; unsigned short* Cb; long long c_bs; int ldc;
  const float* bias0; const float* bias1; const float* bias2;
  const float* decay_ptr;
  const float* gate;
  unsigned short* o_v; unsigned short* o_qd;
  unsigned short* o_kT; unsigned short* o_vTw;
};

// EPI: 0=proj (v16/qd16 + transposed kT16/vTw16), 1=f32+bias (y), 4=bf16 batched (Ut)
template<int EPI>
__global__ __launch_bounds__(256)
void gemm_mfma(MP p) {
  __shared__ unsigned short smem[2 * 128 * 64];   // As | Bs ; reused as 128x128 trans buf
  __shared__ float warr[128];
  unsigned short* As = smem;
  unsigned short* Bs = smem + 128 * 64;
  const int tid = threadIdx.x;
  const int bn = blockIdx.x % p.grid_n, bm = blockIdx.x / p.grid_n;
  const int m0 = bm * 128, n0 = bn * 128;
  const long long z = blockIdx.z;
  const int lane = tid & 63, wv = tid >> 6;
  const int wr = wv >> 1, wc = wv & 1;
  const int srow = tid >> 3, scol = (tid & 7) * 8;

  f32x4 acc[4][4] = {};

  const unsigned short* Abase = p.A + z * p.a_bs + (long long)m0 * p.lda;
  const unsigned short* Bbase = p.B + z * p.b_bs + (long long)n0 * p.ldb;

  for (int k0 = 0; k0 < p.K; k0 += 64) {
    if (k0) __syncthreads();
#pragma unroll
    for (int i = 0; i < 4; i++) {
      int row = i * 32 + srow;
      GLD_LDS(Abase + (long long)row * p.lda + k0 + scol, &As[row * 64 + scol]);
    }
#pragma unroll
    for (int i = 0; i < 4; i++) {
      int row = i * 32 + srow;
      GLD_LDS(Bbase + (long long)row * p.ldb + k0 + scol, &Bs[row * 64 + scol]);
    }
    __syncthreads();
#pragma unroll
    for (int kk = 0; kk < 2; kk++) {
      bf16x8 af[4], bfr[4];
      const int kb = kk * 32 + 8 * (lane >> 4);
#pragma unroll
      for (int m = 0; m < 4; m++)
        af[m] = *(const bf16x8*)&As[(wr * 64 + m * 16 + (lane & 15)) * 64 + kb];
#pragma unroll
      for (int n = 0; n < 4; n++)
        bfr[n] = *(const bf16x8*)&Bs[(wc * 64 + n * 16 + (lane & 15)) * 64 + kb];
#pragma unroll
      for (int m = 0; m < 4; m++)
#pragma unroll
        for (int n = 0; n < 4; n++)
          acc[m][n] = __builtin_amdgcn_mfma_f32_16x16x32_bf16(af[m], bfr[n], acc[m][n], 0, 0, 0);
    }
  }

  if (EPI == 1 || EPI == 4) {
    const int crow0 = m0 + wr * 64, ccol0 = n0 + wc * 64;
#pragma unroll
    for (int m = 0; m < 4; m++) {
#pragma unroll
      for (int n = 0; n < 4; n++) {
        int col = ccol0 + n * 16 + (lane & 15);
#pragma unroll
        for (int q = 0; q < 4; q++) {
          int row = crow0 + m * 16 + (lane >> 4) * 4 + q;
          float v = acc[m][n][q];
          if (EPI == 1) p.Cf[(long long)row * p.ldc + col] = v + p.bias0[col];
          else          p.Cb[z * p.c_bs + (long long)row * p.ldc + col] = f2bf(v);
        }
      }
    }
    return;
  }

  // ---------------- EPI 0: proj epilogue ----------------
  const float log2d = log2f(p.decay_ptr[0]);
  const int sel = bn >> 1;    // 0:k 1:v 2:q
  const int half = bn & 1;

  if (sel < 2) {
    // need LDS as transpose scratch: wait until all waves are done with As/Bs frags
    __syncthreads();
    if (sel == 1 && tid < 128)
      warr[tid] = p.gate[(long long)bm * 128 + tid] * exp2f((float)(127 - tid) * log2d);
  }

#pragma unroll
  for (int m = 0; m < 4; m++) {
#pragma unroll
    for (int n = 0; n < 4; n++) {
      int cl = wc * 64 + n * 16 + (lane & 15);   // local col 0..127
      int d = half * 128 + cl;                   // d_mem index (for sel<2)
      float bias;
      if (sel == 0) bias = p.bias0[d];
      else if (sel == 1) bias = p.bias1[d];
      else bias = p.bias2[(n0 + cl) - 512];
      int r0 = wr * 64 + m * 16 + (lane >> 4) * 4;  // local row base
      if (sel < 2) {
        u16x4 pk;
#pragma unroll
        for (int q = 0; q < 4; q++) {
          float v = acc[m][n][q] + bias;
          pk[q] = f2bf(v);
          if (sel == 1) {
            long long row = m0 + r0 + q;
            p.o_v[row * 256 + d] = pk[q];
          }
        }
        int byteoff = (cl * 256 + r0 * 2) ^ ((cl & 7) << 4);
        *(u16x4*)((char*)smem + byteoff) = pk;
      } else {
#pragma unroll
        for (int q = 0; q < 4; q++) {
          long long row = m0 + r0 + q;
          float v = acc[m][n][q] + bias;
          p.o_qd[row * 256 + ((n0 + cl) - 512)] = f2bf(v * exp2f((float)((r0 + q) & 127) * log2d));
        }
      }
    }
  }

  if (sel < 2) {
    __syncthreads();
    unsigned short* dst = (sel == 0 ? p.o_kT : p.o_vTw) + (long long)bm * 32768;
#pragma unroll
    for (int pp = 0; pp < 8; pp++) {
      int idx = pp * 256 + tid;
      int c = idx >> 4;            // local col (d) 0..127
      int j0 = (idx & 15) * 8;     // row-run start
      u16x8 o = *(const u16x8*)((char*)smem + ((c * 256 + j0 * 2) ^ ((c & 7) << 4)));
      if (sel == 1) {
#pragma unroll
        for (int t = 0; t < 8; t++) o[t] = f2bf(bf2f(o[t]) * warr[j0 + t]);
      }
      *(u16x8*)&dst[(long long)(half * 128 + c) * 128 + j0] = o;
    }
  }
}

// ---------------------------------------------------------------- fused chunk attention
// Block (nh, rh, z): rows roff=rh*64..+64 of chunk z, output cols nh*128..+128.
// p1: A[64x128] = mask(qd@v^T) -> Al (swizzled bf16);  p2a (fused with p1 staging loop):
// acc2 = qd@T^T ;  p2b: acc2 += A@kT^T ;  store mo16.
__global__ __launch_bounds__(512)
void chunk_attn(const unsigned short* __restrict__ qd16, const unsigned short* __restrict__ v16,
                const unsigned short* __restrict__ kT16, const unsigned short* __restrict__ T16,
                unsigned short* __restrict__ mo16, const float* __restrict__ gbuf,
                const float* __restrict__ decay_ptr) {
  __shared__ unsigned short As[64 * 64];        // qd rows (8KB)
  __shared__ unsigned short Bs[2 * 128 * 64];   // v | T (32KB); reused for kT
  __shared__ unsigned short Al[64 * 128];       // swizzled scores (16KB)
  const int tid = threadIdx.x, lane = tid & 63, wv = tid >> 6;
  const int wr = wv >> 2, wc = wv & 3;          // 2 x 4 wave grid
  const int nh = blockIdx.x, rh = blockIdx.y, z = blockIdx.z;
  const int roff = rh * 64;
  const int srow = tid >> 3, scol = (tid & 7) * 8;
  const float log2d = log2f(decay_ptr[0]);

  const unsigned short* qz = qd16 + (long long)z * 32768 + (long long)roff * 256;
  const unsigned short* vz = v16 + (long long)z * 32768;
  const unsigned short* Tz = T16 + (long long)z * 65536 + (long long)nh * 128 * 256;
  const unsigned short* kz = kT16 + (long long)z * 32768 + (long long)nh * 128 * 128;

  f32x4 acc1[2][2] = {};
  f32x4 acc2[2][2] = {};

  // ---- fused phase 1 (scores) + phase 2a (qd@T^T), K=256 ----
  for (int k0 = 0; k0 < 256; k0 += 64) {
    if (k0) __syncthreads();
    GLD_LDS(qz + (long long)srow * 256 + k0 + scol, &As[srow * 64 + scol]);
#pragma unroll
    for (int i = 0; i < 2; i++) {
      int row = i * 64 + srow;
      GLD_LDS(vz + (long long)row * 256 + k0 + scol, &Bs[row * 64 + scol]);
      GLD_LDS(Tz + (long long)row * 256 + k0 + scol, &Bs[8192 + row * 64 + scol]);
    }
    __syncthreads();
#pragma unroll
    for (int kk = 0; kk < 2; kk++) {
      const int kb = kk * 32 + 8 * (lane >> 4);
      bf16x8 af[2], bv[2], bt[2];
#pragma unroll
      for (int m = 0; m < 2; m++)
        af[m] = *(const bf16x8*)&As[(wr * 32 + m * 16 + (lane & 15)) * 64 + kb];
#pragma unroll
      for (int n = 0; n < 2; n++) {
        bv[n] = *(const bf16x8*)&Bs[(wc * 32 + n * 16 + (lane & 15)) * 64 + kb];
        bt[n] = *(const bf16x8*)&Bs[8192 + (wc * 32 + n * 16 + (lane & 15)) * 64 + kb];
      }
#pragma unroll
      for (int m = 0; m < 2; m++)
#pragma unroll
        for (int n = 0; n < 2; n++) {
          acc1[m][n] = __builtin_amdgcn_mfma_f32_16x16x32_bf16(af[m], bv[n], acc1[m][n], 0, 0, 0);
          acc2[m][n] = __builtin_amdgcn_mfma_f32_16x16x32_bf16(af[m], bt[n], acc2[m][n], 0, 0, 0);
        }
    }
  }

  // ---- scores epilogue -> Al (mask, gate-scale, bf16, swizzled) ----
#pragma unroll
  for (int n = 0; n < 2; n++) {
    int col = wc * 32 + n * 16 + (lane & 15);   // j in [0,128)
    float gsc = gbuf[z * 128 + col] * exp2f(-(float)(col + 1) * log2d);
#pragma unroll
    for (int m = 0; m < 2; m++) {
#pragma unroll
      for (int q = 0; q < 4; q++) {
        int r = wr * 32 + m * 16 + (lane >> 4) * 4 + q;   // local row
        float v = (col < roff + r) ? acc1[m][n][q] * gsc : 0.f;
        int byteoff = (r * 256 + col * 2) ^ ((r & 7) << 4);
        *(unsigned short*)((char*)Al + byteoff) = f2bf(v);
      }
    }
  }
  __syncthreads();   // Al visible; all waves done with Bs

  // ---- phase 2b: acc2 += A @ kT^T, K=128 ----
  for (int k0 = 0; k0 < 128; k0 += 64) {
    if (k0) __syncthreads();
#pragma unroll
    for (int i = 0; i < 2; i++) {
      int row = i * 64 + srow;
      GLD_LDS(kz + (long long)row * 128 + k0 + scol, &Bs[row * 64 + scol]);
    }
    __syncthreads();
#pragma unroll
    for (int kk = 0; kk < 2; kk++) {
      const int kbb = k0 + kk * 32 + 8 * (lane >> 4);
      bf16x8 af[2], bk_[2];
#pragma unroll
      for (int m = 0; m < 2; m++) {
        int r = wr * 32 + m * 16 + (lane & 15);
        af[m] = *(const bf16x8*)((char*)Al + ((r * 256 + kbb * 2) ^ ((r & 7) << 4)));
      }
#pragma unroll
      for (int n = 0; n < 2; n++)
        bk_[n] = *(const bf16x8*)&Bs[(wc * 32 + n * 16 + (lane & 15)) * 64 + kk * 32 + 8 * (lane >> 4)];
#pragma unroll
      for (int m = 0; m < 2; m++)
#pragma unroll
        for (int n = 0; n < 2; n++)
          acc2[m][n] = __builtin_amdgcn_mfma_f32_16x16x32_bf16(af[m], bk_[n], acc2[m][n], 0, 0, 0);
    }
  }

  // ---- store mo ----
#pragma unroll
  for (int m = 0; m < 2; m++) {
#pragma unroll
    for (int n = 0; n < 2; n++) {
      int col = nh * 128 + wc * 32 + n * 16 + (lane & 15);
#pragma unroll
      for (int q = 0; q < 4; q++) {
        int row = roff + wr * 32 + m * 16 + (lane >> 4) * 4 + q;
        mo16[((long long)z * 128 + row) * 256 + col] = f2bf(acc2[m][n][q]);
      }
    }
  }
}

// ---------------------------------------------------------------- prep (cast+gate+weight transposes)
__global__ __launch_bounds__(256)
void prep_kernel(const float* __restrict__ x, const float* __restrict__ Wg,
                 const float* __restrict__ bg, unsigned short* __restrict__ x16,
                 float* __restrict__ g,
                 const float* __restrict__ Wk, const float* __restrict__ Wv,
                 const float* __restrict__ Wq, unsigned short* __restrict__ w16,
                 const float* __restrict__ Wo, unsigned short* __restrict__ wot16) {
  __shared__ float tile[64][65];
  const int bx = blockIdx.x;
  const int tid = threadIdx.x;
  if (bx < 2048) {
    const int wave = tid >> 6, lane = tid & 63;
    const long long row = (long long)bx * 4 + wave;
    const float* xr = x + row * 1024 + lane * 16;
    const float* wr = Wg + lane * 16;
    float s = 0.f;
    u16x8 o0, o1;
#pragma unroll
    for (int qq = 0; qq < 2; qq++) {
      float4 a = *(const float4*)(xr + qq * 4);
      float4 w = *(const float4*)(wr + qq * 4);
      s = fmaf(a.x, w.x, s); s = fmaf(a.y, w.y, s);
      s = fmaf(a.z, w.z, s); s = fmaf(a.w, w.w, s);
      o0[qq * 4 + 0] = f2bf(a.x); o0[qq * 4 + 1] = f2bf(a.y);
      o0[qq * 4 + 2] = f2bf(a.z); o0[qq * 4 + 3] = f2bf(a.w);
    }
#pragma unroll
    for (int qq = 0; qq < 2; qq++) {
      float4 a = *(const float4*)(xr + 8 + qq * 4);
      float4 w = *(const float4*)(wr + 8 + qq * 4);
      s = fmaf(a.x, w.x, s); s = fmaf(a.y, w.y, s);
      s = fmaf(a.z, w.z, s); s = fmaf(a.w, w.w, s);
      o1[qq * 4 + 0] = f2bf(a.x); o1[qq * 4 + 1] = f2bf(a.y);
      o1[qq * 4 + 2] = f2bf(a.z); o1[qq * 4 + 3] = f2bf(a.w);
    }
    *(u16x8*)(x16 + row * 1024 + lane * 16) = o0;
    *(u16x8*)(x16 + row * 1024 + lane * 16 + 8) = o1;
#pragma unroll
    for (int off = 32; off; off >>= 1) s += __shfl_xor(s, off, 64);
    if (lane == 0) g[row] = 1.f / (1.f + expf(-(s + bg[0])));
    return;
  }
  int t = bx - 2048;
  const float* S; unsigned short* dst;
  int srcCols, dstLd, k0, n0g, n0;
  if (t < 192) {
    k0 = (t % 16) * 64; n0g = (t / 16) * 64;
    int sel = n0g >> 8; n0 = n0g - (sel << 8);
    S = sel == 0 ? Wk : sel == 1 ? Wv : Wq;
    srcCols = 256; dst = w16; dstLd = 1024;
  } else {
    t -= 192;
    k0 = (t % 4) * 64; n0g = (t / 4) * 64; n0 = n0g;
    S = Wo; srcCols = 1024; dst = wot16; dstLd = 256;
  }
  const int rr = tid >> 4, c4 = (tid & 15) * 4;
#pragma unroll
  for (int pp = 0; pp < 4; pp++) {
    int r = pp * 16 + rr;
    float4 v = *(const float4*)&S[(long long)(k0 + r) * srcCols + n0 + c4];
    tile[r][c4 + 0] = v.x; tile[r][c4 + 1] = v.y; tile[r][c4 + 2] = v.z; tile[r][c4 + 3] = v.w;
  }
  __syncthreads();
  const int rn = tid >> 3, ck0 = (tid & 7) * 8;
#pragma unroll
  for (int pp = 0; pp < 2; pp++) {
    int n = pp * 32 + rn;
    u16x8 o;
#pragma unroll
    for (int j = 0; j < 8; j++) o[j] = f2bf(tile[ck0 + j][n]);
    *(u16x8*)&dst[(long long)(n0g + n) * dstLd + k0 + ck0] = o;
  }
}

// ---------------------------------------------------------------- chunk-state scan
__global__ __launch_bounds__(256)
void scan_kernel(const unsigned short* __restrict__ Ut16, const float* __restrict__ state_in,
                 unsigned short* __restrict__ T16, float* __restrict__ final_out,
                 const float* __restrict__ decay_ptr) {
  int t = blockIdx.x * 256 + threadIdx.x;   // 0..262143
  int b = t >> 16, pidx = t & 65535;        // pidx = e*256+d
  int e = pidx >> 8, d = pidx & 255;
  float dC = exp2f(128.f * log2f(decay_ptr[0]));
  float cur = state_in[(long long)b * 65536 + d * 256 + e];
#pragma unroll
  for (int c = 0; c < 16; c++) {
    long long off = ((long long)(b * 16 + c)) * 65536 + pidx;
    T16[off] = f2bf(cur);
    cur = fmaf(dC, cur, bf2f(Ut16[off]));
  }
  final_out[(long long)b * 65536 + d * 256 + e] = cur;
}

// ---------------------------------------------------------------- launch
extern "C" void kernel_launch(void* const* d_in, const int* in_sizes, int n_in,
                              void* d_out, int out_size, void* d_ws, size_t ws_size,
                              hipStream_t stream) {
  const float* x     = (const float*)d_in[0];
  const float* state = (const float*)d_in[1];
  const float* Wk = (const float*)d_in[2];  const float* bk = (const float*)d_in[3];
  const float* Wv = (const float*)d_in[4];  const float* bv = (const float*)d_in[5];
  const float* Wq = (const float*)d_in[6];  const float* bq = (const float*)d_in[7];
  const float* Wo = (const float*)d_in[8];  const float* bo = (const float*)d_in[9];
  const float* Wg = (const float*)d_in[10]; const float* bg = (const float*)d_in[11];
  const float* decay = (const float*)d_in[12];

  float* out_y = (float*)d_out;              // [4][2048][1024]
  float* out_S = out_y + 8388608;            // [4][256][256]

  float* ws = (float*)d_ws;
  unsigned short* x16   = (unsigned short*)(ws);             // [8192][1024]
  unsigned short* v16   = (unsigned short*)(ws + 4194304);   // [8192][256]
  unsigned short* qd16  = (unsigned short*)(ws + 5242880);   // [8192][256] (q * d^i)
  unsigned short* w16   = (unsigned short*)(ws + 6291456);   // [768][1024]
  unsigned short* wot16 = (unsigned short*)(ws + 6684672);   // [1024][256]
  float*          gbuf  = ws + 6815744;                      // [8192]
  unsigned short* kT16  = (unsigned short*)(ws + 6823936);   // [64][256][128]
  unsigned short* vTw16 = (unsigned short*)(ws + 7872512);   // [64][256][128]
  unsigned short* Ut16  = (unsigned short*)(ws + 8921088);   // [64][256][256]
  unsigned short* T16   = (unsigned short*)(ws + 11018240);  // [64][256][256]
  unsigned short* mo16  = (unsigned short*)(ws + 13115392);  // [8192][256]

  // 1. prep: cast+gate + weight transposes
  prep_kernel<<<2304, 256, 0, stream>>>(x, Wg, bg, x16, gbuf, Wk, Wv, Wq, w16, Wo, wot16);

  // 2. fused projections -> v16, qd16, kT16, vTw16
  {
    MP p{};
    p.A = x16; p.lda = 1024; p.B = w16; p.ldb = 1024;
    p.K = 1024; p.grid_n = 6;
    p.bias0 = bk; p.bias1 = bv; p.bias2 = bq;
    p.decay_ptr = decay; p.gate = gbuf;
    p.o_v = v16; p.o_qd = qd16; p.o_kT = kT16; p.o_vTw = vTw16;
    gemm_mfma<0><<<dim3(384, 1, 1), 256, 0, stream>>>(p);
  }

  // 3. Ut[z] = kT @ vTw^T -> bf16
  {
    MP p{};
    p.A = kT16;  p.a_bs = 32768; p.lda = 128;
    p.B = vTw16; p.b_bs = 32768; p.ldb = 128;
    p.K = 128; p.grid_n = 2;
    p.Cb = Ut16; p.c_bs = 65536; p.ldc = 256;
    p.decay_ptr = decay;
    gemm_mfma<4><<<dim3(4, 1, 64), 256, 0, stream>>>(p);
  }

  // 4. chunk-state scan -> T16 + final_state
  scan_kernel<<<1024, 256, 0, stream>>>(Ut16, state, T16, out_S, decay);

  // 5. fused scores + mem_out
  chunk_attn<<<dim3(2, 2, 64), 512, 0, stream>>>(qd16, v16, kT16, T16, mo16, gbuf, decay);

  // 6. y = mo16 @ wot16^T + bo
  {
    MP p{};
    p.A = mo16; p.lda = 256;
    p.B = wot16; p.ldb = 256;
    p.K = 256; p.grid_n = 8;
    p.Cf = out_y; p.ldc = 1024;
    p.bias0 = bo; p.decay_ptr = decay;
    gemm_mfma<1><<<dim3(512, 1, 1), 256, 0, stream>>>(p);
  }
}

// Round 7
// 93.550 us; speedup vs baseline: 3.9193x; 1.0121x over previous
//
#include <hip/hip_runtime.h>
#include <math.h>

// NeuralMemory: chunked-parallel decaying rank-1 memory scan, all-MFMA version.
//   S_t = decay*S_{t-1} + s_t * v_t k_t^T ;  out_t = q_t^T S_{t-1}
// Chunk C=128, NC=16, b=4, s=2048, d_model=1024, d_mem=256.
//
//  1. prep:      x -> x16 ; gate = sigmoid(x@Wg+bg) ; Wk|Wv|Wq -> w16 ; Wo -> wot16
//  2. proj MFMA: v16, qd16 (qd = q * d^i) = bf16(x16 @ w16^T + bias); epilogue
//                LDS-transposes k/v tiles -> kT16[z][d][j], vTw16[z][d][j] (gate-folded)
//                [XCD-swizzled grid: 6 bn-blocks sharing an A panel sit on one XCD]
//  3. Ut MFMA:   Ut16[z][e][d] = bf16(sum_j kT[e][j] vTw[d][j])   (= U_c^T)
//  4. scan:      T16[z] = bf16(S_c^T) running over chunks; writes final_state
//  5. chunk_attn (per nh,rh,z): A(64x128 rows rh) = mask(qd@v^T) -> LDS swizzled;
//                mo16[64 rows][128 cols nh] = qd@T^T + A@kT^T    (p1/p2a fused)
//  6. y MFMA:    out_y = mo16 @ wot16^T + bo   [XCD-swizzled grid]

using bf16x8 = __attribute__((ext_vector_type(8))) short;
using f32x4  = __attribute__((ext_vector_type(4))) float;
using u16x4  = __attribute__((ext_vector_type(4))) unsigned short;
using u16x8  = __attribute__((ext_vector_type(8))) unsigned short;

__device__ inline unsigned short f2bf(float f) {
  unsigned int u = __float_as_uint(f);
  u = (u + 0x7FFF + ((u >> 16) & 1)) >> 16;
  return (unsigned short)u;
}
__device__ inline float bf2f(unsigned short u) {
  return __uint_as_float(((unsigned int)u) << 16);
}

#define GLD_LDS(gsrc, ldst) \
  __builtin_amdgcn_global_load_lds( \
      (const __attribute__((address_space(1))) unsigned int*)(gsrc), \
      (__attribute__((address_space(3))) unsigned int*)(ldst), 16, 0, 0)

// ---------------------------------------------------------------- MFMA GEMM
// C = A[M][K] * B[N][K]^T, 128x128 tile, BK=64, 4 waves, global_load_lds staging.
struct MP {
  const unsigned short* A; long long a_bs; int lda;
  const unsigned short* B; long long b_bs; int ldb;
  int K, grid_n;
  int swz;                                    // 1: XCD-chunked blockIdx swizzle
  float* Cf; unsigned short* Cb; long long c_bs; int ldc;
  const float* bias0; const float* bias1; const float* bias2;
  const float* decay_ptr;
  const float* gate;
  unsigned short* o_v; unsigned short* o_qd;
  unsigned short* o_kT; unsigned short* o_vTw;
};

// EPI: 0=proj (v16/qd16 + transposed kT16/vTw16), 1=f32+bias (y), 4=bf16 batched (Ut)
template<int EPI>
__global__ __launch_bounds__(256)
void gemm_mfma(MP p) {
  __shared__ unsigned short smem[2 * 128 * 64];   // As | Bs ; reused as 128x128 trans buf
  __shared__ float warr[128];
  unsigned short* As = smem;
  unsigned short* Bs = smem + 128 * 64;
  const int tid = threadIdx.x;
  // XCD-aware bijective swizzle (requires gridDim.x % 8 == 0): XCD i gets a
  // contiguous chunk of logical tiles so bn-blocks sharing an A panel share an L2.
  const int bid = p.swz ? ((blockIdx.x & 7) * (gridDim.x >> 3) + (blockIdx.x >> 3))
                        : blockIdx.x;
  const int bn = bid % p.grid_n, bm = bid / p.grid_n;
  const int m0 = bm * 128, n0 = bn * 128;
  const long long z = blockIdx.z;
  const int lane = tid & 63, wv = tid >> 6;
  const int wr = wv >> 1, wc = wv & 1;
  const int srow = tid >> 3, scol = (tid & 7) * 8;

  f32x4 acc[4][4] = {};

  const unsigned short* Abase = p.A + z * p.a_bs + (long long)m0 * p.lda;
  const unsigned short* Bbase = p.B + z * p.b_bs + (long long)n0 * p.ldb;

  for (int k0 = 0; k0 < p.K; k0 += 64) {
    if (k0) __syncthreads();
#pragma unroll
    for (int i = 0; i < 4; i++) {
      int row = i * 32 + srow;
      GLD_LDS(Abase + (long long)row * p.lda + k0 + scol, &As[row * 64 + scol]);
    }
#pragma unroll
    for (int i = 0; i < 4; i++) {
      int row = i * 32 + srow;
      GLD_LDS(Bbase + (long long)row * p.ldb + k0 + scol, &Bs[row * 64 + scol]);
    }
    __syncthreads();
#pragma unroll
    for (int kk = 0; kk < 2; kk++) {
      bf16x8 af[4], bfr[4];
      const int kb = kk * 32 + 8 * (lane >> 4);
#pragma unroll
      for (int m = 0; m < 4; m++)
        af[m] = *(const bf16x8*)&As[(wr * 64 + m * 16 + (lane & 15)) * 64 + kb];
#pragma unroll
      for (int n = 0; n < 4; n++)
        bfr[n] = *(const bf16x8*)&Bs[(wc * 64 + n * 16 + (lane & 15)) * 64 + kb];
#pragma unroll
      for (int m = 0; m < 4; m++)
#pragma unroll
        for (int n = 0; n < 4; n++)
          acc[m][n] = __builtin_amdgcn_mfma_f32_16x16x32_bf16(af[m], bfr[n], acc[m][n], 0, 0, 0);
    }
  }

  if (EPI == 1 || EPI == 4) {
    const int crow0 = m0 + wr * 64, ccol0 = n0 + wc * 64;
#pragma unroll
    for (int m = 0; m < 4; m++) {
#pragma unroll
      for (int n = 0; n < 4; n++) {
        int col = ccol0 + n * 16 + (lane & 15);
#pragma unroll
        for (int q = 0; q < 4; q++) {
          int row = crow0 + m * 16 + (lane >> 4) * 4 + q;
          float v = acc[m][n][q];
          if (EPI == 1) p.Cf[(long long)row * p.ldc + col] = v + p.bias0[col];
          else          p.Cb[z * p.c_bs + (long long)row * p.ldc + col] = f2bf(v);
        }
      }
    }
    return;
  }

  // ---------------- EPI 0: proj epilogue ----------------
  const float log2d = log2f(p.decay_ptr[0]);
  const int sel = bn >> 1;    // 0:k 1:v 2:q
  const int half = bn & 1;

  if (sel < 2) {
    // need LDS as transpose scratch: wait until all waves are done with As/Bs frags
    __syncthreads();
    if (sel == 1 && tid < 128)
      warr[tid] = p.gate[(long long)bm * 128 + tid] * exp2f((float)(127 - tid) * log2d);
  }

#pragma unroll
  for (int m = 0; m < 4; m++) {
#pragma unroll
    for (int n = 0; n < 4; n++) {
      int cl = wc * 64 + n * 16 + (lane & 15);   // local col 0..127
      int d = half * 128 + cl;                   // d_mem index (for sel<2)
      float bias;
      if (sel == 0) bias = p.bias0[d];
      else if (sel == 1) bias = p.bias1[d];
      else bias = p.bias2[(n0 + cl) - 512];
      int r0 = wr * 64 + m * 16 + (lane >> 4) * 4;  // local row base
      if (sel < 2) {
        u16x4 pk;
#pragma unroll
        for (int q = 0; q < 4; q++) {
          float v = acc[m][n][q] + bias;
          pk[q] = f2bf(v);
          if (sel == 1) {
            long long row = m0 + r0 + q;
            p.o_v[row * 256 + d] = pk[q];
          }
        }
        int byteoff = (cl * 256 + r0 * 2) ^ ((cl & 7) << 4);
        *(u16x4*)((char*)smem + byteoff) = pk;
      } else {
#pragma unroll
        for (int q = 0; q < 4; q++) {
          long long row = m0 + r0 + q;
          float v = acc[m][n][q] + bias;
          p.o_qd[row * 256 + ((n0 + cl) - 512)] = f2bf(v * exp2f((float)((r0 + q) & 127) * log2d));
        }
      }
    }
  }

  if (sel < 2) {
    __syncthreads();
    unsigned short* dst = (sel == 0 ? p.o_kT : p.o_vTw) + (long long)bm * 32768;
#pragma unroll
    for (int pp = 0; pp < 8; pp++) {
      int idx = pp * 256 + tid;
      int c = idx >> 4;            // local col (d) 0..127
      int j0 = (idx & 15) * 8;     // row-run start
      u16x8 o = *(const u16x8*)((char*)smem + ((c * 256 + j0 * 2) ^ ((c & 7) << 4)));
      if (sel == 1) {
#pragma unroll
        for (int t = 0; t < 8; t++) o[t] = f2bf(bf2f(o[t]) * warr[j0 + t]);
      }
      *(u16x8*)&dst[(long long)(half * 128 + c) * 128 + j0] = o;
    }
  }
}

// ---------------------------------------------------------------- fused chunk attention
// Block (nh, rh, z): rows roff=rh*64..+64 of chunk z, output cols nh*128..+128.
// p1: A[64x128] = mask(qd@v^T) -> Al (swizzled bf16);  p2a (fused with p1 staging loop):
// acc2 = qd@T^T ;  p2b: acc2 += A@kT^T ;  store mo16.
__global__ __launch_bounds__(512)
void chunk_attn(const unsigned short* __restrict__ qd16, const unsigned short* __restrict__ v16,
                const unsigned short* __restrict__ kT16, const unsigned short* __restrict__ T16,
                unsigned short* __restrict__ mo16, const float* __restrict__ gbuf,
                const float* __restrict__ decay_ptr) {
  __shared__ unsigned short As[64 * 64];        // qd rows (8KB)
  __shared__ unsigned short Bs[2 * 128 * 64];   // v | T (32KB); reused for kT
  __shared__ unsigned short Al[64 * 128];       // swizzled scores (16KB)
  const int tid = threadIdx.x, lane = tid & 63, wv = tid >> 6;
  const int wr = wv >> 2, wc = wv & 3;          // 2 x 4 wave grid
  const int nh = blockIdx.x, rh = blockIdx.y, z = blockIdx.z;
  const int roff = rh * 64;
  const int srow = tid >> 3, scol = (tid & 7) * 8;
  const float log2d = log2f(decay_ptr[0]);

  const unsigned short* qz = qd16 + (long long)z * 32768 + (long long)roff * 256;
  const unsigned short* vz = v16 + (long long)z * 32768;
  const unsigned short* Tz = T16 + (long long)z * 65536 + (long long)nh * 128 * 256;
  const unsigned short* kz = kT16 + (long long)z * 32768 + (long long)nh * 128 * 128;

  f32x4 acc1[2][2] = {};
  f32x4 acc2[2][2] = {};

  // ---- fused phase 1 (scores) + phase 2a (qd@T^T), K=256 ----
  for (int k0 = 0; k0 < 256; k0 += 64) {
    if (k0) __syncthreads();
    GLD_LDS(qz + (long long)srow * 256 + k0 + scol, &As[srow * 64 + scol]);
#pragma unroll
    for (int i = 0; i < 2; i++) {
      int row = i * 64 + srow;
      GLD_LDS(vz + (long long)row * 256 + k0 + scol, &Bs[row * 64 + scol]);
      GLD_LDS(Tz + (long long)row * 256 + k0 + scol, &Bs[8192 + row * 64 + scol]);
    }
    __syncthreads();
#pragma unroll
    for (int kk = 0; kk < 2; kk++) {
      const int kb = kk * 32 + 8 * (lane >> 4);
      bf16x8 af[2], bv[2], bt[2];
#pragma unroll
      for (int m = 0; m < 2; m++)
        af[m] = *(const bf16x8*)&As[(wr * 32 + m * 16 + (lane & 15)) * 64 + kb];
#pragma unroll
      for (int n = 0; n < 2; n++) {
        bv[n] = *(const bf16x8*)&Bs[(wc * 32 + n * 16 + (lane & 15)) * 64 + kb];
        bt[n] = *(const bf16x8*)&Bs[8192 + (wc * 32 + n * 16 + (lane & 15)) * 64 + kb];
      }
#pragma unroll
      for (int m = 0; m < 2; m++)
#pragma unroll
        for (int n = 0; n < 2; n++) {
          acc1[m][n] = __builtin_amdgcn_mfma_f32_16x16x32_bf16(af[m], bv[n], acc1[m][n], 0, 0, 0);
          acc2[m][n] = __builtin_amdgcn_mfma_f32_16x16x32_bf16(af[m], bt[n], acc2[m][n], 0, 0, 0);
        }
    }
  }

  // ---- scores epilogue -> Al (mask, gate-scale, bf16, swizzled) ----
#pragma unroll
  for (int n = 0; n < 2; n++) {
    int col = wc * 32 + n * 16 + (lane & 15);   // j in [0,128)
    float gsc = gbuf[z * 128 + col] * exp2f(-(float)(col + 1) * log2d);
#pragma unroll
    for (int m = 0; m < 2; m++) {
#pragma unroll
      for (int q = 0; q < 4; q++) {
        int r = wr * 32 + m * 16 + (lane >> 4) * 4 + q;   // local row
        float v = (col < roff + r) ? acc1[m][n][q] * gsc : 0.f;
        int byteoff = (r * 256 + col * 2) ^ ((r & 7) << 4);
        *(unsigned short*)((char*)Al + byteoff) = f2bf(v);
      }
    }
  }
  __syncthreads();   // Al visible; all waves done with Bs

  // ---- phase 2b: acc2 += A @ kT^T, K=128 ----
  for (int k0 = 0; k0 < 128; k0 += 64) {
    if (k0) __syncthreads();
#pragma unroll
    for (int i = 0; i < 2; i++) {
      int row = i * 64 + srow;
      GLD_LDS(kz + (long long)row * 128 + k0 + scol, &Bs[row * 64 + scol]);
    }
    __syncthreads();
#pragma unroll
    for (int kk = 0; kk < 2; kk++) {
      const int kbb = k0 + kk * 32 + 8 * (lane >> 4);
      bf16x8 af[2], bk_[2];
#pragma unroll
      for (int m = 0; m < 2; m++) {
        int r = wr * 32 + m * 16 + (lane & 15);
        af[m] = *(const bf16x8*)((char*)Al + ((r * 256 + kbb * 2) ^ ((r & 7) << 4)));
      }
#pragma unroll
      for (int n = 0; n < 2; n++)
        bk_[n] = *(const bf16x8*)&Bs[(wc * 32 + n * 16 + (lane & 15)) * 64 + kk * 32 + 8 * (lane >> 4)];
#pragma unroll
      for (int m = 0; m < 2; m++)
#pragma unroll
        for (int n = 0; n < 2; n++)
          acc2[m][n] = __builtin_amdgcn_mfma_f32_16x16x32_bf16(af[m], bk_[n], acc2[m][n], 0, 0, 0);
    }
  }

  // ---- store mo ----
#pragma unroll
  for (int m = 0; m < 2; m++) {
#pragma unroll
    for (int n = 0; n < 2; n++) {
      int col = nh * 128 + wc * 32 + n * 16 + (lane & 15);
#pragma unroll
      for (int q = 0; q < 4; q++) {
        int row = roff + wr * 32 + m * 16 + (lane >> 4) * 4 + q;
        mo16[((long long)z * 128 + row) * 256 + col] = f2bf(acc2[m][n][q]);
      }
    }
  }
}

// ---------------------------------------------------------------- prep (cast+gate+weight transposes)
__global__ __launch_bounds__(256)
void prep_kernel(const float* __restrict__ x, const float* __restrict__ Wg,
                 const float* __restrict__ bg, unsigned short* __restrict__ x16,
                 float* __restrict__ g,
                 const float* __restrict__ Wk, const float* __restrict__ Wv,
                 const float* __restrict__ Wq, unsigned short* __restrict__ w16,
                 const float* __restrict__ Wo, unsigned short* __restrict__ wot16) {
  __shared__ float tile[64][65];
  const int bx = blockIdx.x;
  const int tid = threadIdx.x;
  if (bx < 2048) {
    const int wave = tid >> 6, lane = tid & 63;
    const long long row = (long long)bx * 4 + wave;
    const float* xr = x + row * 1024 + lane * 16;
    const float* wr = Wg + lane * 16;
    float s = 0.f;
    u16x8 o0, o1;
#pragma unroll
    for (int qq = 0; qq < 2; qq++) {
      float4 a = *(const float4*)(xr + qq * 4);
      float4 w = *(const float4*)(wr + qq * 4);
      s = fmaf(a.x, w.x, s); s = fmaf(a.y, w.y, s);
      s = fmaf(a.z, w.z, s); s = fmaf(a.w, w.w, s);
      o0[qq * 4 + 0] = f2bf(a.x); o0[qq * 4 + 1] = f2bf(a.y);
      o0[qq * 4 + 2] = f2bf(a.z); o0[qq * 4 + 3] = f2bf(a.w);
    }
#pragma unroll
    for (int qq = 0; qq < 2; qq++) {
      float4 a = *(const float4*)(xr + 8 + qq * 4);
      float4 w = *(const float4*)(wr + 8 + qq * 4);
      s = fmaf(a.x, w.x, s); s = fmaf(a.y, w.y, s);
      s = fmaf(a.z, w.z, s); s = fmaf(a.w, w.w, s);
      o1[qq * 4 + 0] = f2bf(a.x); o1[qq * 4 + 1] = f2bf(a.y);
      o1[qq * 4 + 2] = f2bf(a.z); o1[qq * 4 + 3] = f2bf(a.w);
    }
    *(u16x8*)(x16 + row * 1024 + lane * 16) = o0;
    *(u16x8*)(x16 + row * 1024 + lane * 16 + 8) = o1;
#pragma unroll
    for (int off = 32; off; off >>= 1) s += __shfl_xor(s, off, 64);
    if (lane == 0) g[row] = 1.f / (1.f + expf(-(s + bg[0])));
    return;
  }
  int t = bx - 2048;
  const float* S; unsigned short* dst;
  int srcCols, dstLd, k0, n0g, n0;
  if (t < 192) {
    k0 = (t % 16) * 64; n0g = (t / 16) * 64;
    int sel = n0g >> 8; n0 = n0g - (sel << 8);
    S = sel == 0 ? Wk : sel == 1 ? Wv : Wq;
    srcCols = 256; dst = w16; dstLd = 1024;
  } else {
    t -= 192;
    k0 = (t % 4) * 64; n0g = (t / 4) * 64; n0 = n0g;
    S = Wo; srcCols = 1024; dst = wot16; dstLd = 256;
  }
  const int rr = tid >> 4, c4 = (tid & 15) * 4;
#pragma unroll
  for (int pp = 0; pp < 4; pp++) {
    int r = pp * 16 + rr;
    float4 v = *(const float4*)&S[(long long)(k0 + r) * srcCols + n0 + c4];
    tile[r][c4 + 0] = v.x; tile[r][c4 + 1] = v.y; tile[r][c4 + 2] = v.z; tile[r][c4 + 3] = v.w;
  }
  __syncthreads();
  const int rn = tid >> 3, ck0 = (tid & 7) * 8;
#pragma unroll
  for (int pp = 0; pp < 2; pp++) {
    int n = pp * 32 + rn;
    u16x8 o;
#pragma unroll
    for (int j = 0; j < 8; j++) o[j] = f2bf(tile[ck0 + j][n]);
    *(u16x8*)&dst[(long long)(n0g + n) * dstLd + k0 + ck0] = o;
  }
}

// ---------------------------------------------------------------- chunk-state scan
__global__ __launch_bounds__(256)
void scan_kernel(const unsigned short* __restrict__ Ut16, const float* __restrict__ state_in,
                 unsigned short* __restrict__ T16, float* __restrict__ final_out,
                 const float* __restrict__ decay_ptr) {
  int t = blockIdx.x * 256 + threadIdx.x;   // 0..262143
  int b = t >> 16, pidx = t & 65535;        // pidx = e*256+d
  int e = pidx >> 8, d = pidx & 255;
  float dC = exp2f(128.f * log2f(decay_ptr[0]));
  float cur = state_in[(long long)b * 65536 + d * 256 + e];
#pragma unroll
  for (int c = 0; c < 16; c++) {
    long long off = ((long long)(b * 16 + c)) * 65536 + pidx;
    T16[off] = f2bf(cur);
    cur = fmaf(dC, cur, bf2f(Ut16[off]));
  }
  final_out[(long long)b * 65536 + d * 256 + e] = cur;
}

// ---------------------------------------------------------------- launch
extern "C" void kernel_launch(void* const* d_in, const int* in_sizes, int n_in,
                              void* d_out, int out_size, void* d_ws, size_t ws_size,
                              hipStream_t stream) {
  const float* x     = (const float*)d_in[0];
  const float* state = (const float*)d_in[1];
  const float* Wk = (const float*)d_in[2];  const float* bk = (const float*)d_in[3];
  const float* Wv = (const float*)d_in[4];  const float* bv = (const float*)d_in[5];
  const float* Wq = (const float*)d_in[6];  const float* bq = (const float*)d_in[7];
  const float* Wo = (const float*)d_in[8];  const float* bo = (const float*)d_in[9];
  const float* Wg = (const float*)d_in[10]; const float* bg = (const float*)d_in[11];
  const float* decay = (const float*)d_in[12];

  float* out_y = (float*)d_out;              // [4][2048][1024]
  float* out_S = out_y + 8388608;            // [4][256][256]

  float* ws = (float*)d_ws;
  unsigned short* x16   = (unsigned short*)(ws);             // [8192][1024]
  unsigned short* v16   = (unsigned short*)(ws + 4194304);   // [8192][256]
  unsigned short* qd16  = (unsigned short*)(ws + 5242880);   // [8192][256] (q * d^i)
  unsigned short* w16   = (unsigned short*)(ws + 6291456);   // [768][1024]
  unsigned short* wot16 = (unsigned short*)(ws + 6684672);   // [1024][256]
  float*          gbuf  = ws + 6815744;                      // [8192]
  unsigned short* kT16  = (unsigned short*)(ws + 6823936);   // [64][256][128]
  unsigned short* vTw16 = (unsigned short*)(ws + 7872512);   // [64][256][128]
  unsigned short* Ut16  = (unsigned short*)(ws + 8921088);   // [64][256][256]
  unsigned short* T16   = (unsigned short*)(ws + 11018240);  // [64][256][256]
  unsigned short* mo16  = (unsigned short*)(ws + 13115392);  // [8192][256]

  // 1. prep: cast+gate + weight transposes
  prep_kernel<<<2304, 256, 0, stream>>>(x, Wg, bg, x16, gbuf, Wk, Wv, Wq, w16, Wo, wot16);

  // 2. fused projections -> v16, qd16, kT16, vTw16  (XCD-swizzled, 384 % 8 == 0)
  {
    MP p{};
    p.A = x16; p.lda = 1024; p.B = w16; p.ldb = 1024;
    p.K = 1024; p.grid_n = 6; p.swz = 1;
    p.bias0 = bk; p.bias1 = bv; p.bias2 = bq;
    p.decay_ptr = decay; p.gate = gbuf;
    p.o_v = v16; p.o_qd = qd16; p.o_kT = kT16; p.o_vTw = vTw16;
    gemm_mfma<0><<<dim3(384, 1, 1), 256, 0, stream>>>(p);
  }

  // 3. Ut[z] = kT @ vTw^T -> bf16
  {
    MP p{};
    p.A = kT16;  p.a_bs = 32768; p.lda = 128;
    p.B = vTw16; p.b_bs = 32768; p.ldb = 128;
    p.K = 128; p.grid_n = 2; p.swz = 0;
    p.Cb = Ut16; p.c_bs = 65536; p.ldc = 256;
    p.decay_ptr = decay;
    gemm_mfma<4><<<dim3(4, 1, 64), 256, 0, stream>>>(p);
  }

  // 4. chunk-state scan -> T16 + final_state
  scan_kernel<<<1024, 256, 0, stream>>>(Ut16, state, T16, out_S, decay);

  // 5. fused scores + mem_out
  chunk_attn<<<dim3(2, 2, 64), 512, 0, stream>>>(qd16, v16, kT16, T16, mo16, gbuf, decay);

  // 6. y = mo16 @ wot16^T + bo  (XCD-swizzled, 512 % 8 == 0)
  {
    MP p{};
    p.A = mo16; p.lda = 256;
    p.B = wot16; p.ldb = 256;
    p.K = 256; p.grid_n = 8; p.swz = 1;
    p.Cf = out_y; p.ldc = 1024;
    p.bias0 = bo; p.decay_ptr = decay;
    gemm_mfma<1><<<dim3(512, 1, 1), 256, 0, stream>>>(p);
  }
}